// Round 5
// baseline (241.520 us; speedup 1.0000x reference)
//
#include <hip/hip_runtime.h>
#include <hip/hip_bf16.h>

#define EMBED 1024
#define NHEADS 16
#define HDIM 64
#define NB 2
#define NSEQ 2048
#define NTOK (NB*NSEQ)   // 4096

using short8  = __attribute__((ext_vector_type(8))) short;
using short4v = __attribute__((ext_vector_type(4))) short;
using f32x4   = __attribute__((ext_vector_type(4))) float;

#define INV_LN2 1.4426950408889634f

__device__ __forceinline__ short f2bf(float x) {
  __hip_bfloat16 h = __float2bfloat16(x);
  short s;
  __builtin_memcpy(&s, &h, 2);
  return s;
}

#define GLDS16(gp, lp) __builtin_amdgcn_global_load_lds( \
    (const __attribute__((address_space(1))) unsigned int*)(const void*)(gp), \
    (__attribute__((address_space(3))) unsigned int*)(void*)(lp), 16, 0, 0)

#define BAR() __builtin_amdgcn_s_barrier()
#define WAITVM(N) asm volatile("s_waitcnt vmcnt(" #N ")" ::: "memory")

// ---------------- LayerNorm: f32 [4096][1024] -> bf16 xn ----------------
__global__ __launch_bounds__(256) void ln_kernel(const float* __restrict__ x,
    const float* __restrict__ gamma, const float* __restrict__ beta,
    short* __restrict__ xn) {
  const int row = blockIdx.x;
  const int tid = threadIdx.x;
  const float* xr = x + (size_t)row * EMBED;
  float4 v = *(const float4*)(xr + tid * 4);
  float s  = v.x + v.y + v.z + v.w;
  float s2 = v.x*v.x + v.y*v.y + v.z*v.z + v.w*v.w;
#pragma unroll
  for (int off = 32; off; off >>= 1) {
    s  += __shfl_down(s, off);
    s2 += __shfl_down(s2, off);
  }
  __shared__ float red[8];
  const int wv = tid >> 6, ln = tid & 63;
  if (ln == 0) { red[wv] = s; red[4 + wv] = s2; }
  __syncthreads();
  s  = red[0] + red[1] + red[2] + red[3];
  s2 = red[4] + red[5] + red[6] + red[7];
  const float mu  = s * (1.0f / EMBED);
  const float var = s2 * (1.0f / EMBED) - mu * mu;
  const float inv = rsqrtf(var + 1e-5f);
  float4 g  = *(const float4*)(gamma + tid * 4);
  float4 bt = *(const float4*)(beta + tid * 4);
  short4v o;
  o[0] = f2bf((v.x - mu) * inv * g.x + bt.x);
  o[1] = f2bf((v.y - mu) * inv * g.y + bt.y);
  o[2] = f2bf((v.z - mu) * inv * g.z + bt.z);
  o[3] = f2bf((v.w - mu) * inv * g.w + bt.w);
  *(short4v*)(xn + (size_t)row * EMBED + tid * 4) = o;
}

// ---------------- weight cast: 4 x 1M f32 -> bf16 ----------------
__global__ __launch_bounds__(256) void cast4_kernel(
    const float* __restrict__ a, const float* __restrict__ b,
    const float* __restrict__ c, const float* __restrict__ d,
    short* __restrict__ oa, short* __restrict__ ob,
    short* __restrict__ oc, short* __restrict__ od) {
  const int wsel = blockIdx.y;
  const float* s = (wsel == 0) ? a : (wsel == 1) ? b : (wsel == 2) ? c : d;
  short* o       = (wsel == 0) ? oa : (wsel == 1) ? ob : (wsel == 2) ? oc : od;
  const int i = (blockIdx.x * 256 + threadIdx.x) * 4;
  float4 v = *(const float4*)(s + i);
  short4v r;
  r[0] = f2bf(v.x); r[1] = f2bf(v.y); r[2] = f2bf(v.z); r[3] = f2bf(v.w);
  *(short4v*)(o + i) = r;
}

// ---------------- QKV GEMM: 256x256 tile, BK=64, 8 waves, 4-phase/K-tile ----------------
// Deep-pipelined (T2 swizzle + counted vmcnt + setprio). Grid (12, 16): tn>>2 selects Q/K/V.
__global__ __launch_bounds__(512, 2) void qkv_kernel(
    const short* __restrict__ A,
    const short* __restrict__ W0, const short* __restrict__ W1, const short* __restrict__ W2,
    const float* __restrict__ b0, const float* __restrict__ b1, const float* __restrict__ b2,
    short* __restrict__ O0, short* __restrict__ O1, short* __restrict__ O2) {
  constexpr int K = 1024, kNT = 16;
  const int tn = blockIdx.x, tm = blockIdx.y;
  const int sel = tn >> 2;
  const short* Bw   = (sel == 0) ? W0 : (sel == 1) ? W1 : W2;
  const float* bias = (sel == 0) ? b0 : (sel == 1) ? b1 : b2;
  short* Cout       = (sel == 0) ? O0 : (sel == 1) ? O1 : O2;
  const int ncol0 = (tn & 3) * 256;

  const int tid = threadIdx.x;
  const int w = tid >> 6, lane = tid & 63;
  const int wr = w >> 2, wc = w & 3;        // wave grid 2(M) x 4(N); per-wave 128x64
  const int g = lane >> 4, c = lane & 15;

  __shared__ short As[2][256 * 64];   // [row m][k ^ ((m&7)<<3)] via pre-swizzled source
  __shared__ short Bs[2][256 * 64];   // [row n][k ^ ((n&7)<<3)]

  f32x4 acc[8][4];
#pragma unroll
  for (int i = 0; i < 8; i++)
#pragma unroll
    for (int j = 0; j < 4; j++) acc[i][j] = (f32x4){0.f, 0.f, 0.f, 0.f};

  const int sr  = tid >> 3;            // 0..63
  const int sc8 = (tid & 7) * 8;
  const int ssw = (sr & 7) << 3;
  const short* ga = A  + (size_t)(tm * 256) * K;
  const short* gb = Bw + (size_t)ncol0 * K;

  // staging units: A-unit0 rows {sr, 128+sr}, A-unit1 {64+sr, 192+sr} (match m-half retirement);
  // B-unit0 rows 0..127, B-unit1 128..255 (B retired every ph0).
  auto stA = [&](int buf, int unit, int kt) {
#pragma unroll
    for (int i = 0; i < 2; i++) {
      const int row = unit * 64 + i * 128 + sr;
      GLDS16(ga + (size_t)row * K + kt * 64 + (sc8 ^ ssw), &As[buf][row * 64 + sc8]);
    }
  };
  auto stB = [&](int buf, int unit, int kt) {
#pragma unroll
    for (int i = 0; i < 2; i++) {
      const int row = unit * 128 + i * 64 + sr;
      GLDS16(gb + (size_t)row * K + kt * 64 + (sc8 ^ ssw), &Bs[buf][row * 64 + sc8]);
    }
  };

  short8 af[4][2], bf[4][2];

  auto ldA = [&](const short* as, int mh) {
#pragma unroll
    for (int mi = 0; mi < 4; mi++) {
      const int row = wr * 128 + mh * 64 + mi * 16 + c;
      const int sw = (row & 7) << 3;
#pragma unroll
      for (int ks = 0; ks < 2; ks++)
        af[mi][ks] = *(const short8*)&as[row * 64 + ((ks * 32 + g * 8) ^ sw)];
    }
  };
  auto MF = [&](int mh, int nh) {
#pragma unroll
    for (int ks = 0; ks < 2; ks++)
#pragma unroll
      for (int mi = 0; mi < 4; mi++)
#pragma unroll
        for (int ni = 0; ni < 2; ni++)
          acc[mh * 4 + mi][nh * 2 + ni] = __builtin_amdgcn_mfma_f32_16x16x32_bf16(
              af[mi][ks], bf[nh * 2 + ni][ks], acc[mh * 4 + mi][nh * 2 + ni], 0, 0, 0);
  };

  // ---- prologue: stage kt0 (8 loads) then kt1 (8 loads); wait kt0; barrier ----
  stA(0, 0, 0); stA(0, 1, 0); stB(0, 0, 0); stB(0, 1, 0);
  stA(1, 0, 1); stA(1, 1, 1); stB(1, 0, 1); stB(1, 1, 1);
  WAITVM(8);
  BAR();

  for (int kt = 0; kt < kNT; ++kt) {
    const int cb = kt & 1;
    const short* as = As[cb];
    const short* bs = Bs[cb];
    const bool pre = (kt + 2 < kNT);

    // ---- ph0: read A mh0 (8 b128) + all B (16 b128); MFMA quadrant (0,0)
    ldA(as, 0);
#pragma unroll
    for (int ni = 0; ni < 4; ni++) {
      const int row = wc * 64 + ni * 16 + c;
      const int sw = (row & 7) << 3;
#pragma unroll
      for (int ks = 0; ks < 2; ks++)
        bf[ni][ks] = *(const short8*)&bs[row * 64 + ((ks * 32 + g * 8) ^ sw)];
    }
    BAR();
    __builtin_amdgcn_s_setprio(1);
    MF(0, 0);
    __builtin_amdgcn_s_setprio(0);
    BAR();

    // ---- ph1: stage A-unit0(kt+2); MFMA (0,1)
    if (pre) stA(cb, 0, kt + 2);
    BAR();
    __builtin_amdgcn_s_setprio(1);
    MF(0, 1);
    __builtin_amdgcn_s_setprio(0);
    BAR();

    // ---- ph2: read A mh1; stage B-unit0(kt+2); MFMA (1,0)
    ldA(as, 1);
    if (pre) stB(cb, 0, kt + 2);
    BAR();
    __builtin_amdgcn_s_setprio(1);
    MF(1, 0);
    __builtin_amdgcn_s_setprio(0);
    BAR();

    // ---- ph3: stage A-unit1 + B-unit1(kt+2); MFMA (1,1); counted vmcnt; barrier
    if (pre) { stA(cb, 1, kt + 2); stB(cb, 1, kt + 2); }
    BAR();
    __builtin_amdgcn_s_setprio(1);
    MF(1, 1);
    __builtin_amdgcn_s_setprio(0);
    if (pre) { WAITVM(8); } else if (kt + 1 < kNT) { WAITVM(0); }
    BAR();
  }

  // ---- epilogue: bias + bf16 store ----
#pragma unroll
  for (int ni4 = 0; ni4 < 4; ni4++) {
    const int no = (ni4 >> 1) * 32 + (ni4 & 1) * 16;
    const int lcol = ncol0 + wc * 64 + no + c;
    const float bsv = bias[lcol];
#pragma unroll
    for (int mi8 = 0; mi8 < 8; mi8++) {
      const int mo = (mi8 >> 2) * 64 + (mi8 & 3) * 16;
      const int row = tm * 256 + wr * 128 + mo + g * 4;
#pragma unroll
      for (int j = 0; j < 4; j++)
        Cout[(size_t)(row + j) * 1024 + lcol] = f2bf(acc[mi8][ni4][j] + bsv);
    }
  }
}

// ---------------- GEMM (proj): C[M][1024] = A[M][1024] @ W^T + bias ----------------
template<bool F32OUT>
__global__ __launch_bounds__(256) void gemm_kernel(
    const short* __restrict__ A,
    const short* __restrict__ W0, const short* __restrict__ W1, const short* __restrict__ W2,
    const float* __restrict__ b0, const float* __restrict__ b1, const float* __restrict__ b2,
    void* __restrict__ O0, void* __restrict__ O1, void* __restrict__ O2) {
  constexpr int K = 1024, NOUT = 1024;
  const int z = blockIdx.z;
  const short* Bw   = (z == 0) ? W0 : (z == 1) ? W1 : W2;
  const float* bias = (z == 0) ? b0 : (z == 1) ? b1 : b2;
  void* Cout        = (z == 0) ? O0 : (z == 1) ? O1 : O2;

  const int tn = blockIdx.x, tm = blockIdx.y;
  const int tid = threadIdx.x, w = tid >> 6, lane = tid & 63;
  const int wm = w >> 1, wn = w & 1;
  const int g = lane >> 4, c = lane & 15;

  __shared__ short As[128 * 32];
  __shared__ short Bs[128 * 32];

  f32x4 acc[4][4];
#pragma unroll
  for (int i = 0; i < 4; i++)
#pragma unroll
    for (int j = 0; j < 4; j++) acc[i][j] = (f32x4){0.f, 0.f, 0.f, 0.f};

  const int crow = tid >> 2;
  const int ckc  = tid & 3;
  const short* ga = A  + (size_t)(tm * 128 + crow) * K + ckc * 8;
  const short* gb = Bw + (size_t)(tn * 128 + crow) * K + ckc * 8;
  short* la = &As[tid * 8];
  short* lb = &Bs[tid * 8];

  for (int k0 = 0; k0 < K; k0 += 32) {
    __syncthreads();
    GLDS16(ga + k0, la);
    GLDS16(ga + k0 + (size_t)64 * K, la + 64 * 32);
    GLDS16(gb + k0, lb);
    GLDS16(gb + k0 + (size_t)64 * K, lb + 64 * 32);
    __syncthreads();
    short8 af[4], bfr[4];
#pragma unroll
    for (int mi = 0; mi < 4; mi++)
      af[mi] = *(const short8*)&As[(wm * 64 + mi * 16 + c) * 32 + g * 8];
#pragma unroll
    for (int ni = 0; ni < 4; ni++)
      bfr[ni] = *(const short8*)&Bs[(wn * 64 + ni * 16 + c) * 32 + g * 8];
#pragma unroll
    for (int mi = 0; mi < 4; mi++)
#pragma unroll
      for (int ni = 0; ni < 4; ni++)
        acc[mi][ni] = __builtin_amdgcn_mfma_f32_16x16x32_bf16(af[mi], bfr[ni], acc[mi][ni], 0, 0, 0);
  }

#pragma unroll
  for (int ni = 0; ni < 4; ni++) {
    const int col = tn * 128 + wn * 64 + ni * 16 + c;
    const float bs = bias[col];
#pragma unroll
    for (int mi = 0; mi < 4; mi++) {
#pragma unroll
      for (int j = 0; j < 4; j++) {
        const int row = tm * 128 + wm * 64 + mi * 16 + g * 4 + j;
        const float v = acc[mi][ni][j] + bs;
        if constexpr (F32OUT)
          ((float*)Cout)[(size_t)row * NOUT + col] = v;
        else
          ((short*)Cout)[(size_t)row * NOUT + col] = f2bf(v);
      }
    }
  }
}

// ---------------- V transpose: [n][h*64+d] -> [b][h][d][n(2048)] ----------------
__global__ __launch_bounds__(256) void vtrans_kernel(const short* __restrict__ vb,
                                                     short* __restrict__ vt) {
  const int n0 = blockIdx.x * 64;
  const int bh = blockIdx.y;
  const int b = bh >> 4, h = bh & 15;
  const int tid = threadIdx.x;
  __shared__ short tl[64 * 68];

  const int r  = tid >> 3;
  const int c8 = (tid & 7) * 8;
#pragma unroll
  for (int i = 0; i < 2; i++) {
    const int row = r + i * 32;
    short8 v = *(const short8*)(vb + (size_t)(b * NSEQ + n0 + row) * EMBED + h * 64 + c8);
    *(short8*)&tl[row * 68 + c8] = v;
  }
  __syncthreads();
  const int d  = tid >> 2;
  const int ns = (tid & 3) * 16;
  short8 o0, o1;
#pragma unroll
  for (int e = 0; e < 8; e++) {
    o0[e] = tl[(ns + e) * 68 + d];
    o1[e] = tl[(ns + 8 + e) * 68 + d];
  }
  short* dst = vt + ((size_t)((b * 16 + h) * 64 + d)) * 2048 + n0 + ns;
  *(short8*)dst = o0;
  *(short8*)(dst + 8) = o1;
}

// ---------------- Flash attention: 8 waves x 16 q-rows (128 rows/block) ----------------
__global__ __launch_bounds__(512, 4) void attn_kernel(
    const short* __restrict__ Qm, const short* __restrict__ Km, const short* __restrict__ Vt,
    const float* __restrict__ relb, short* __restrict__ ctx) {
  const int bid = blockIdx.x;
  const int bh  = bid & 31;
  const int idx = bid >> 5;
  const int qpair = (idx < 8) ? (15 - idx) : (idx - 8);
  const int b = bh >> 4, h = bh & 15;
  const int tid = threadIdx.x, w = tid >> 6, lane = tid & 63;
  const int g = lane >> 4, c = lane & 15;
  constexpr float S31 = 31.0f / 2047.0f;

  __shared__ short k_lds[2][64 * 64];
  __shared__ short vt_lds[2][64 * 64];
  __shared__ short p_lds[8][16 * 64];
  __shared__ float rrow[128][33];

  const int qbase = qpair * 128;
  const size_t bhq = (size_t)b * NSEQ * EMBED + h * HDIM;
  const short* vtb = Vt + (size_t)((b << 4) + h) * 64 * 2048;

  short8 qf[2];
  {
    const short* qp = Qm + bhq + (size_t)(qbase + w * 16 + c) * EMBED;
    qf[0] = *(const short8*)(qp + g * 8);
    qf[1] = *(const short8*)(qp + 32 + g * 8);
  }

  const int srow = tid >> 3;
  const int sd0  = (tid & 7) * 8;
  const int swz  = (srow & 7) << 3;

  GLDS16(Km + bhq + (size_t)srow * EMBED + (sd0 ^ swz), &k_lds[0][srow * 64 + sd0]);
  GLDS16(vtb + (size_t)srow * 2048 + (sd0 ^ swz),       &vt_lds[0][srow * 64 + sd0]);
  for (int i = tid; i < 128 * 32; i += 512) {
    const int qr = i >> 5, jj = i & 31;
    const int qg0 = qbase + qr;
    float rv = 0.f;
    if (qg0 != NSEQ - 1) {
      const float pos = qg0 * S31;
      const int i0 = (int)pos;
      const int i1 = min(i0 + 1, 31);
      const float fr = pos - (float)i0;
      const float* T = relb + h * 1024;
      rv = ((1.f - fr) * T[i0 * 32 + jj] + fr * T[i1 * 32 + jj]) * INV_LN2;
    }
    rrow[qr][jj] = rv;
  }
  __syncthreads();

  float mrow = -3.0e38f, lrow = 0.f;
  f32x4 oacc[4];
#pragma unroll
  for (int db = 0; db < 4; db++) oacc[db] = (f32x4){0.f, 0.f, 0.f, 0.f};

  const int qg  = qbase + w * 16 + c;
  const int qhi = qbase + w * 16 + 15;
  const float* rr = &rrow[w * 16 + c][0];
  const int csw = (c & 7) << 3;
  const int nkv = 2 * qpair + 2;

  for (int kt = 0; kt < nkv; kt++) {
    const int cur = kt & 1;
    const int kv0 = kt * 64;

    if (kt + 1 < nkv) {
      GLDS16(Km + bhq + (size_t)(kv0 + 64 + srow) * EMBED + (sd0 ^ swz),
             &k_lds[cur ^ 1][srow * 64 + sd0]);
      GLDS16(vtb + (size_t)srow * 2048 + (kv0 + 64) + (sd0 ^ swz),
             &vt_lds[cur ^ 1][srow * 64 + sd0]);
    }

    if (kv0 <= qhi) {
      const short* kl = &k_lds[cur][0];
      const short* vl = &vt_lds[cur][0];

      f32x4 st[4];
#pragma unroll
      for (int mb = 0; mb < 4; mb++) st[mb] = (f32x4){0.f, 0.f, 0.f, 0.f};
      __builtin_amdgcn_s_setprio(1);
#pragma unroll
      for (int kh = 0; kh < 2; kh++) {
        const int dk = kh * 32 + g * 8;
#pragma unroll
        for (int mb = 0; mb < 4; mb++) {
          const int row = mb * 16 + c;
          short8 kf = *(const short8*)&kl[row * 64 + (dk ^ ((row & 7) << 3))];
          st[mb] = __builtin_amdgcn_mfma_f32_16x16x32_bf16(kf, qf[kh], st[mb], 0, 0, 0);
        }
      }
      __builtin_amdgcn_s_setprio(0);

      float p[4][4];
      float pmax = -3.0e38f;
      const bool diag = (kv0 + 63 > qg);
      const int I = (int)(kv0 * S31);
      const float rA = rr[I];
      const float rB = rr[I + 1];
      const float rC = rr[min(I + 2, 31)];
      const float dAB = rB - rA, dBC = rC - rB;
#pragma unroll
      for (int mb = 0; mb < 4; mb++) {
#pragma unroll
        for (int j = 0; j < 4; j++) {
          const int mg = kv0 + mb * 16 + g * 4 + j;
          const float pos = mg * S31;
          const int i0 = (int)pos;
          const float fr = pos - (float)i0;
          const bool sel = i0 > I;
          float sv = st[mb][j] * (0.125f * INV_LN2);
          if (mg != NSEQ - 1) sv += fmaf(fr, sel ? dBC : dAB, sel ? rB : rA);
          if (diag && mg > qg) sv = -3.0e38f;
          p[mb][j] = sv;
          pmax = fmaxf(pmax, sv);
        }
      }
      pmax = fmaxf(pmax, __shfl_xor(pmax, 16));
      pmax = fmaxf(pmax, __shfl_xor(pmax, 32));

      if (!__all(pmax - mrow <= 11.6f)) {
        const float mnew = fmaxf(mrow, pmax);
        const float al = exp2f(mrow - mnew);
        mrow = mnew;
        lrow *= al;
        float alj[4];
#pragma unroll
        for (int j = 0; j < 4; j++) alj[j] = __shfl(al, g * 4 + j);
#pragma unroll
        for (int db = 0; db < 4; db++)
#pragma unroll
          for (int j = 0; j < 4; j++) oacc[db][j] *= alj[j];
      }

      float rs = 0.f;
#pragma unroll
      for (int mb = 0; mb < 4; mb++)
#pragma unroll
        for (int j = 0; j < 4; j++) {
          const float pe = exp2f(p[mb][j] - mrow);
          p[mb][j] = pe;
          rs += pe;
        }
      rs += __shfl_xor(rs, 16);
      rs += __shfl_xor(rs, 32);
      lrow += rs;

      short* pw = &p_lds[w][0];
#pragma unroll
      for (int mb = 0; mb < 4; mb++)
#pragma unroll
        for (int jh = 0; jh < 2; jh++) {
          const int m = mb * 16 + g * 4 + jh * 2;
          unsigned int pk = ((unsigned int)(unsigned short)f2bf(p[mb][jh * 2 + 1]) << 16)
                          |  (unsigned int)(unsigned short)f2bf(p[mb][jh * 2]);
          *(unsigned int*)&pw[c * 64 + (m ^ csw)] = pk;
        }

      __builtin_amdgcn_s_setprio(1);
#pragma unroll
      for (int kb = 0; kb < 2; kb++) {
        const int m0 = kb * 32 + g * 8;
        short8 pa = *(const short8*)&pw[c * 64 + (m0 ^ csw)];
#pragma unroll
        for (int db = 0; db < 4; db++) {
          const int d = db * 16 + c;
          short8 vf = *(const short8*)&vl[d * 64 + (m0 ^ ((d & 7) << 3))];
          oacc[db] = __builtin_amdgcn_mfma_f32_16x16x32_bf16(pa, vf, oacc[db], 0, 0, 0);
        }
      }
      __builtin_amdgcn_s_setprio(0);
    }
    __syncthreads();
  }

  float linv[4];
#pragma unroll
  for (int j = 0; j < 4; j++) linv[j] = 1.f / __shfl(lrow, g * 4 + j);
#pragma unroll
  for (int j = 0; j < 4; j++) {
    short* op = ctx + bhq + (size_t)(qbase + w * 16 + g * 4 + j) * EMBED;
#pragma unroll
    for (int db = 0; db < 4; db++)
      op[db * 16 + c] = f2bf(oacc[db][j] * linv[j]);
  }
}

extern "C" void kernel_launch(void* const* d_in, const int* in_sizes, int n_in,
                              void* d_out, int out_size, void* d_ws, size_t ws_size,
                              hipStream_t stream) {
  const float* x     = (const float*)d_in[0];
  const float* Wq    = (const float*)d_in[1];
  const float* bq    = (const float*)d_in[2];
  const float* Wk    = (const float*)d_in[3];
  const float* bk    = (const float*)d_in[4];
  const float* Wv    = (const float*)d_in[5];
  const float* bv    = (const float*)d_in[6];
  const float* Wo    = (const float*)d_in[7];
  const float* bo    = (const float*)d_in[8];
  const float* gamma = (const float*)d_in[9];
  const float* beta  = (const float*)d_in[10];
  const float* relb  = (const float*)d_in[11];
  float* out = (float*)d_out;

  char* ws = (char*)d_ws;
  short* xn  = (short*)ws; ws += (size_t)NTOK * EMBED * 2;   // reused as vtb after QKV GEMM
  short* wqb = (short*)ws; ws += (size_t)EMBED * EMBED * 2;
  short* wkb = (short*)ws; ws += (size_t)EMBED * EMBED * 2;
  short* wvb = (short*)ws; ws += (size_t)EMBED * EMBED * 2;
  short* wob = (short*)ws; ws += (size_t)EMBED * EMBED * 2;
  short* qb  = (short*)ws; ws += (size_t)NTOK * EMBED * 2;
  short* kb_ = (short*)ws; ws += (size_t)NTOK * EMBED * 2;
  short* vb  = (short*)ws; ws += (size_t)NTOK * EMBED * 2;
  short* ctx = (short*)ws; ws += (size_t)NTOK * EMBED * 2;
  short* vtb = xn;

  ln_kernel<<<dim3(NTOK), dim3(256), 0, stream>>>(x, gamma, beta, xn);
  cast4_kernel<<<dim3(1024, 4), dim3(256), 0, stream>>>(Wq, Wk, Wv, Wo, wqb, wkb, wvb, wob);
  qkv_kernel<<<dim3(12, 16), dim3(512), 0, stream>>>(
      xn, wqb, wkb, wvb, bq, bk, bv, qb, kb_, vb);
  vtrans_kernel<<<dim3(32, 32), dim3(256), 0, stream>>>(vb, vtb);
  attn_kernel<<<dim3(512), dim3(512), 0, stream>>>(qb, kb_, vtb, relb, ctx);
  gemm_kernel<true><<<dim3(8, 32, 1), dim3(256), 0, stream>>>(
      ctx, wob, wob, wob, bo, bo, bo, (void*)out, (void*)out, (void*)out);
}

// Round 6
// 217.681 us; speedup vs baseline: 1.1095x; 1.1095x over previous
//
#include <hip/hip_runtime.h>
#include <hip/hip_bf16.h>

#define EMBED 1024
#define NHEADS 16
#define HDIM 64
#define NB 2
#define NSEQ 2048
#define NTOK (NB*NSEQ)   // 4096

using short8  = __attribute__((ext_vector_type(8))) short;
using short4v = __attribute__((ext_vector_type(4))) short;
using f32x4   = __attribute__((ext_vector_type(4))) float;

#define INV_LN2 1.4426950408889634f

__device__ __forceinline__ short f2bf(float x) {
  __hip_bfloat16 h = __float2bfloat16(x);
  short s;
  __builtin_memcpy(&s, &h, 2);
  return s;
}

#define GLDS16(gp, lp) __builtin_amdgcn_global_load_lds( \
    (const __attribute__((address_space(1))) unsigned int*)(const void*)(gp), \
    (__attribute__((address_space(3))) unsigned int*)(void*)(lp), 16, 0, 0)

// ---------------- LayerNorm: f32 [4096][1024] -> bf16 xn ----------------
__global__ __launch_bounds__(256) void ln_kernel(const float* __restrict__ x,
    const float* __restrict__ gamma, const float* __restrict__ beta,
    short* __restrict__ xn) {
  const int row = blockIdx.x;
  const int tid = threadIdx.x;
  const float* xr = x + (size_t)row * EMBED;
  float4 v = *(const float4*)(xr + tid * 4);
  float s  = v.x + v.y + v.z + v.w;
  float s2 = v.x*v.x + v.y*v.y + v.z*v.z + v.w*v.w;
#pragma unroll
  for (int off = 32; off; off >>= 1) {
    s  += __shfl_down(s, off);
    s2 += __shfl_down(s2, off);
  }
  __shared__ float red[8];
  const int wv = tid >> 6, ln = tid & 63;
  if (ln == 0) { red[wv] = s; red[4 + wv] = s2; }
  __syncthreads();
  s  = red[0] + red[1] + red[2] + red[3];
  s2 = red[4] + red[5] + red[6] + red[7];
  const float mu  = s * (1.0f / EMBED);
  const float var = s2 * (1.0f / EMBED) - mu * mu;
  const float inv = rsqrtf(var + 1e-5f);
  float4 g  = *(const float4*)(gamma + tid * 4);
  float4 bt = *(const float4*)(beta + tid * 4);
  short4v o;
  o[0] = f2bf((v.x - mu) * inv * g.x + bt.x);
  o[1] = f2bf((v.y - mu) * inv * g.y + bt.y);
  o[2] = f2bf((v.z - mu) * inv * g.z + bt.z);
  o[3] = f2bf((v.w - mu) * inv * g.w + bt.w);
  *(short4v*)(xn + (size_t)row * EMBED + tid * 4) = o;
}

// ---------------- weight cast: 4 x 1M f32 -> bf16 ----------------
__global__ __launch_bounds__(256) void cast4_kernel(
    const float* __restrict__ a, const float* __restrict__ b,
    const float* __restrict__ c, const float* __restrict__ d,
    short* __restrict__ oa, short* __restrict__ ob,
    short* __restrict__ oc, short* __restrict__ od) {
  const int wsel = blockIdx.y;
  const float* s = (wsel == 0) ? a : (wsel == 1) ? b : (wsel == 2) ? c : d;
  short* o       = (wsel == 0) ? oa : (wsel == 1) ? ob : (wsel == 2) ? oc : od;
  const int i = (blockIdx.x * 256 + threadIdx.x) * 4;
  float4 v = *(const float4*)(s + i);
  short4v r;
  r[0] = f2bf(v.x); r[1] = f2bf(v.y); r[2] = f2bf(v.z); r[3] = f2bf(v.w);
  *(short4v*)(o + i) = r;
}

// ---------------- GEMM: C[M][1024] = A[M][1024] @ W^T + bias ----------------
// 128x128 tile, BK=32, 4 waves, global_load_lds staging (m97 structure; proven round-4).
template<bool F32OUT>
__global__ __launch_bounds__(256) void gemm_kernel(
    const short* __restrict__ A,
    const short* __restrict__ W0, const short* __restrict__ W1, const short* __restrict__ W2,
    const float* __restrict__ b0, const float* __restrict__ b1, const float* __restrict__ b2,
    void* __restrict__ O0, void* __restrict__ O1, void* __restrict__ O2) {
  constexpr int K = 1024, NOUT = 1024;
  const int z = blockIdx.z;
  const short* Bw   = (z == 0) ? W0 : (z == 1) ? W1 : W2;
  const float* bias = (z == 0) ? b0 : (z == 1) ? b1 : b2;
  void* Cout        = (z == 0) ? O0 : (z == 1) ? O1 : O2;

  const int tn = blockIdx.x, tm = blockIdx.y;
  const int tid = threadIdx.x, w = tid >> 6, lane = tid & 63;
  const int wm = w >> 1, wn = w & 1;
  const int g = lane >> 4, c = lane & 15;

  __shared__ short As[128 * 32];
  __shared__ short Bs[128 * 32];

  f32x4 acc[4][4];
#pragma unroll
  for (int i = 0; i < 4; i++)
#pragma unroll
    for (int j = 0; j < 4; j++) acc[i][j] = (f32x4){0.f, 0.f, 0.f, 0.f};

  const int crow = tid >> 2;
  const int ckc  = tid & 3;
  const short* ga = A  + (size_t)(tm * 128 + crow) * K + ckc * 8;
  const short* gb = Bw + (size_t)(tn * 128 + crow) * K + ckc * 8;
  short* la = &As[tid * 8];
  short* lb = &Bs[tid * 8];

  for (int k0 = 0; k0 < K; k0 += 32) {
    __syncthreads();
    GLDS16(ga + k0, la);
    GLDS16(ga + k0 + (size_t)64 * K, la + 64 * 32);
    GLDS16(gb + k0, lb);
    GLDS16(gb + k0 + (size_t)64 * K, lb + 64 * 32);
    __syncthreads();
    short8 af[4], bfr[4];
#pragma unroll
    for (int mi = 0; mi < 4; mi++)
      af[mi] = *(const short8*)&As[(wm * 64 + mi * 16 + c) * 32 + g * 8];
#pragma unroll
    for (int ni = 0; ni < 4; ni++)
      bfr[ni] = *(const short8*)&Bs[(wn * 64 + ni * 16 + c) * 32 + g * 8];
#pragma unroll
    for (int mi = 0; mi < 4; mi++)
#pragma unroll
      for (int ni = 0; ni < 4; ni++)
        acc[mi][ni] = __builtin_amdgcn_mfma_f32_16x16x32_bf16(af[mi], bfr[ni], acc[mi][ni], 0, 0, 0);
  }

#pragma unroll
  for (int ni = 0; ni < 4; ni++) {
    const int col = tn * 128 + wn * 64 + ni * 16 + c;
    const float bs = bias[col];
#pragma unroll
    for (int mi = 0; mi < 4; mi++) {
#pragma unroll
      for (int j = 0; j < 4; j++) {
        const int row = tm * 128 + wm * 64 + mi * 16 + g * 4 + j;
        const float v = acc[mi][ni][j] + bs;
        if constexpr (F32OUT)
          ((float*)Cout)[(size_t)row * NOUT + col] = v;
        else
          ((short*)Cout)[(size_t)row * NOUT + col] = f2bf(v);
      }
    }
  }
}

// ---------------- V transpose: [n][h*64+d] -> [b][h][d][n(2048)] ----------------
__global__ __launch_bounds__(256) void vtrans_kernel(const short* __restrict__ vb,
                                                     short* __restrict__ vt) {
  const int n0 = blockIdx.x * 64;
  const int bh = blockIdx.y;
  const int b = bh >> 4, h = bh & 15;
  const int tid = threadIdx.x;
  __shared__ short tl[64 * 68];

  const int r  = tid >> 3;
  const int c8 = (tid & 7) * 8;
#pragma unroll
  for (int i = 0; i < 2; i++) {
    const int row = r + i * 32;
    short8 v = *(const short8*)(vb + (size_t)(b * NSEQ + n0 + row) * EMBED + h * 64 + c8);
    *(short8*)&tl[row * 68 + c8] = v;
  }
  __syncthreads();
  const int d  = tid >> 2;
  const int ns = (tid & 3) * 16;
  short8 o0, o1;
#pragma unroll
  for (int e = 0; e < 8; e++) {
    o0[e] = tl[(ns + e) * 68 + d];
    o1[e] = tl[(ns + 8 + e) * 68 + d];
  }
  short* dst = vt + ((size_t)((b * 16 + h) * 64 + d)) * 2048 + n0 + ns;
  *(short8*)dst = o0;
  *(short8*)(dst + 8) = o1;
}

// ---------------- Flash attention: 8 waves x 16 q-rows, bias folded into MFMA ----------------
// rel[q][m] = U[m][:] . R[q][:]  (U = per-tile m-interp weights, R = q-interp'd bias x8).
__global__ __launch_bounds__(512, 4) void attn_kernel(
    const short* __restrict__ Qm, const short* __restrict__ Km, const short* __restrict__ Vt,
    const float* __restrict__ relb, short* __restrict__ ctx) {
  const int bid = blockIdx.x;
  const int bh  = bid & 31;
  const int idx = bid >> 5;
  const int qpair = (idx < 8) ? (15 - idx) : (idx - 8);
  const int b = bh >> 4, h = bh & 15;
  const int tid = threadIdx.x, w = tid >> 6, lane = tid & 63;
  const int g = lane >> 4, c = lane & 15;
  constexpr float S31 = 31.0f / 2047.0f;
  constexpr float CSC = 0.125f * INV_LN2;   // common scale (log2 domain)

  __shared__ short k_lds[2][64 * 64];   // [m][d ^ ((m&7)<<3)] via pre-swizzled glds source
  __shared__ short vt_lds[2][64 * 64];  // [d][m ^ ((d&7)<<3)]
  __shared__ short p_lds[8][16 * 64];   // per-wave P: [q=c][m ^ ((c&7)<<3)]
  __shared__ short rbf[128 * 32];       // R: q-interp'd bias * 8, bf16
  __shared__ short u_lds[2][64 * 40];   // U: per-tile m-interp weights, pad 40

  const int qbase = qpair * 128;
  const size_t bhq = (size_t)b * NSEQ * EMBED + h * HDIM;
  const short* vtb = Vt + (size_t)((b << 4) + h) * 64 * 2048;

  // Q fragments: q-row = qbase + w*16 + c (MFMA B-operand of swapped QK^T)
  short8 qf[2];
  {
    const short* qp = Qm + bhq + (size_t)(qbase + w * 16 + c) * EMBED;
    qf[0] = *(const short8*)(qp + g * 8);
    qf[1] = *(const short8*)(qp + 32 + g * 8);
  }

  const int srow = tid >> 3;
  const int sd0  = (tid & 7) * 8;
  const int swz  = (srow & 7) << 3;

  // U-build (wave 0): row tid = local m; 2 nonzeros; zero row for m==2047
  auto buildU = [&](int buf, int kv) {
    if (tid < 64) {
      short* ur = &u_lds[buf][tid * 40];
      *(int4*)&ur[0]  = (int4){0, 0, 0, 0};
      *(int4*)&ur[8]  = (int4){0, 0, 0, 0};
      *(int4*)&ur[16] = (int4){0, 0, 0, 0};
      *(int4*)&ur[24] = (int4){0, 0, 0, 0};
      const int m = kv + tid;
      if (m != NSEQ - 1) {
        const float pos = m * S31;
        const int i0 = (int)pos;
        const float fr = pos - (float)i0;
        ur[i0]     = f2bf(1.0f - fr);
        ur[i0 + 1] = f2bf(fr);
      }
    }
  };

  // ---- prologue: stage tile 0; build R (x8); build U for tile 0 ----
  GLDS16(Km + bhq + (size_t)srow * EMBED + (sd0 ^ swz), &k_lds[0][srow * 64 + sd0]);
  GLDS16(vtb + (size_t)srow * 2048 + (sd0 ^ swz),       &vt_lds[0][srow * 64 + sd0]);
  for (int i = tid; i < 128 * 32; i += 512) {
    const int qr = i >> 5, jj = i & 31;
    const int qg0 = qbase + qr;
    float rv = 0.f;
    if (qg0 != NSEQ - 1) {
      const float pos = qg0 * S31;
      const int i0 = (int)pos;
      const int i1 = min(i0 + 1, 31);
      const float fr = pos - (float)i0;
      const float* T = relb + h * 1024;
      rv = ((1.f - fr) * T[i0 * 32 + jj] + fr * T[i1 * 32 + jj]) * 8.0f;
    }
    rbf[i] = f2bf(rv);
  }
  buildU(0, 0);
  __syncthreads();

  // R fragment for this lane's q-row (constant over tiles)
  const short8 rq = *(const short8*)&rbf[(w * 16 + c) * 32 + g * 8];

  float mrow = -3.0e38f, lrow = 0.f;
  f32x4 oacc[4];
#pragma unroll
  for (int db = 0; db < 4; db++) oacc[db] = (f32x4){0.f, 0.f, 0.f, 0.f};

  const int qg  = qbase + w * 16 + c;
  const int qhi = qbase + w * 16 + 15;
  const int csw = (c & 7) << 3;
  const int nkv = 2 * qpair + 2;

  for (int kt = 0; kt < nkv; kt++) {
    const int cur = kt & 1;
    const int kv0 = kt * 64;

    if (kt + 1 < nkv) {
      GLDS16(Km + bhq + (size_t)(kv0 + 64 + srow) * EMBED + (sd0 ^ swz),
             &k_lds[cur ^ 1][srow * 64 + sd0]);
      GLDS16(vtb + (size_t)srow * 2048 + (kv0 + 64) + (sd0 ^ swz),
             &vt_lds[cur ^ 1][srow * 64 + sd0]);
      buildU(cur ^ 1, kv0 + 64);
    }

    if (kv0 <= qhi) {
      const short* kl = &k_lds[cur][0];
      const short* vl = &vt_lds[cur][0];
      const short* ul = &u_lds[cur][0];

      // S^T = K Q^T + U R^T : lane (g,c) gets st[q=c][m = mb*16 + g*4 + j]
      f32x4 st[4];
#pragma unroll
      for (int mb = 0; mb < 4; mb++) st[mb] = (f32x4){0.f, 0.f, 0.f, 0.f};
      __builtin_amdgcn_s_setprio(1);
#pragma unroll
      for (int kh = 0; kh < 2; kh++) {
        const int dk = kh * 32 + g * 8;
#pragma unroll
        for (int mb = 0; mb < 4; mb++) {
          const int row = mb * 16 + c;
          short8 kf = *(const short8*)&kl[row * 64 + (dk ^ ((row & 7) << 3))];
          st[mb] = __builtin_amdgcn_mfma_f32_16x16x32_bf16(kf, qf[kh], st[mb], 0, 0, 0);
        }
      }
#pragma unroll
      for (int mb = 0; mb < 4; mb++) {
        short8 uf = *(const short8*)&ul[(mb * 16 + c) * 40 + g * 8];
        st[mb] = __builtin_amdgcn_mfma_f32_16x16x32_bf16(uf, rq, st[mb], 0, 0, 0);
      }
      __builtin_amdgcn_s_setprio(0);

      // causal mask on raw st (diag tiles only), then max in raw domain
      const bool diag = (kv0 + 63 > qg);
      if (diag) {
#pragma unroll
        for (int mb = 0; mb < 4; mb++)
#pragma unroll
          for (int j = 0; j < 4; j++) {
            const int mg = kv0 + mb * 16 + g * 4 + j;
            if (mg > qg) st[mb][j] = -1.0e38f;
          }
      }
      float pmr = -3.0e38f;
#pragma unroll
      for (int mb = 0; mb < 4; mb++)
#pragma unroll
        for (int j = 0; j < 4; j++) pmr = fmaxf(pmr, st[mb][j]);
      float pmax = pmr * CSC;
      pmax = fmaxf(pmax, __shfl_xor(pmax, 16));
      pmax = fmaxf(pmax, __shfl_xor(pmax, 32));

      if (!__all(pmax - mrow <= 11.6f)) {        // defer-max (log2 units)
        const float mnew = fmaxf(mrow, pmax);
        const float al = exp2f(mrow - mnew);
        mrow = mnew;
        lrow *= al;
        float alj[4];
#pragma unroll
        for (int j = 0; j < 4; j++) alj[j] = __shfl(al, g * 4 + j);
#pragma unroll
        for (int db = 0; db < 4; db++)
#pragma unroll
          for (int j = 0; j < 4; j++) oacc[db][j] *= alj[j];
      }

      float p[4][4];
      float rs = 0.f;
#pragma unroll
      for (int mb = 0; mb < 4; mb++)
#pragma unroll
        for (int j = 0; j < 4; j++) {
          const float pe = exp2f(fmaf(st[mb][j], CSC, -mrow));
          p[mb][j] = pe;
          rs += pe;
        }
      rs += __shfl_xor(rs, 16);
      rs += __shfl_xor(rs, 32);
      lrow += rs;

      // P -> p_lds (bf16 pairs, swizzled), wave-local
      short* pw = &p_lds[w][0];
#pragma unroll
      for (int mb = 0; mb < 4; mb++)
#pragma unroll
        for (int jh = 0; jh < 2; jh++) {
          const int m = mb * 16 + g * 4 + jh * 2;
          unsigned int pk = ((unsigned int)(unsigned short)f2bf(p[mb][jh * 2 + 1]) << 16)
                          |  (unsigned int)(unsigned short)f2bf(p[mb][jh * 2]);
          *(unsigned int*)&pw[c * 64 + (m ^ csw)] = pk;
        }

      // O += P V
      __builtin_amdgcn_s_setprio(1);
#pragma unroll
      for (int kb = 0; kb < 2; kb++) {
        const int m0 = kb * 32 + g * 8;
        short8 pa = *(const short8*)&pw[c * 64 + (m0 ^ csw)];
#pragma unroll
        for (int db = 0; db < 4; db++) {
          const int d = db * 16 + c;
          short8 vf = *(const short8*)&vl[d * 64 + (m0 ^ ((d & 7) << 3))];
          oacc[db] = __builtin_amdgcn_mfma_f32_16x16x32_bf16(pa, vf, oacc[db], 0, 0, 0);
        }
      }
      __builtin_amdgcn_s_setprio(0);
    }
    __syncthreads();
  }

  // epilogue: redistribute l to D-domain rows, normalize, store
  float linv[4];
#pragma unroll
  for (int j = 0; j < 4; j++) linv[j] = 1.f / __shfl(lrow, g * 4 + j);
#pragma unroll
  for (int j = 0; j < 4; j++) {
    short* op = ctx + bhq + (size_t)(qbase + w * 16 + g * 4 + j) * EMBED;
#pragma unroll
    for (int db = 0; db < 4; db++)
      op[db * 16 + c] = f2bf(oacc[db][j] * linv[j]);
  }
}

extern "C" void kernel_launch(void* const* d_in, const int* in_sizes, int n_in,
                              void* d_out, int out_size, void* d_ws, size_t ws_size,
                              hipStream_t stream) {
  const float* x     = (const float*)d_in[0];
  const float* Wq    = (const float*)d_in[1];
  const float* bq    = (const float*)d_in[2];
  const float* Wk    = (const float*)d_in[3];
  const float* bk    = (const float*)d_in[4];
  const float* Wv    = (const float*)d_in[5];
  const float* bv    = (const float*)d_in[6];
  const float* Wo    = (const float*)d_in[7];
  const float* bo    = (const float*)d_in[8];
  const float* gamma = (const float*)d_in[9];
  const float* beta  = (const float*)d_in[10];
  const float* relb  = (const float*)d_in[11];
  float* out = (float*)d_out;

  char* ws = (char*)d_ws;
  short* xn  = (short*)ws; ws += (size_t)NTOK * EMBED * 2;   // reused as vtb after QKV GEMM
  short* wqb = (short*)ws; ws += (size_t)EMBED * EMBED * 2;
  short* wkb = (short*)ws; ws += (size_t)EMBED * EMBED * 2;
  short* wvb = (short*)ws; ws += (size_t)EMBED * EMBED * 2;
  short* wob = (short*)ws; ws += (size_t)EMBED * EMBED * 2;
  short* qb  = (short*)ws; ws += (size_t)NTOK * EMBED * 2;
  short* kb_ = (short*)ws; ws += (size_t)NTOK * EMBED * 2;
  short* vb  = (short*)ws; ws += (size_t)NTOK * EMBED * 2;
  short* ctx = (short*)ws; ws += (size_t)NTOK * EMBED * 2;
  short* vtb = xn;

  ln_kernel<<<dim3(NTOK), dim3(256), 0, stream>>>(x, gamma, beta, xn);
  cast4_kernel<<<dim3(1024, 4), dim3(256), 0, stream>>>(Wq, Wk, Wv, Wo, wqb, wkb, wvb, wob);
  gemm_kernel<false><<<dim3(8, 32, 3), dim3(256), 0, stream>>>(
      xn, wqb, wkb, wvb, bq, bk, bv, (void*)qb, (void*)kb_, (void*)vb);
  vtrans_kernel<<<dim3(32, 32), dim3(256), 0, stream>>>(vb, vtb);
  attn_kernel<<<dim3(512), dim3(512), 0, stream>>>(qb, kb_, vtb, relb, ctx);
  gemm_kernel<true><<<dim3(8, 32, 1), dim3(256), 0, stream>>>(
      ctx, wob, wob, wob, bo, bo, bo, (void*)out, (void*)out, (void*)out);
}

// Round 7
// 213.599 us; speedup vs baseline: 1.1307x; 1.0191x over previous
//
#include <hip/hip_runtime.h>
#include <hip/hip_bf16.h>

#define EMBED 1024
#define NHEADS 16
#define HDIM 64
#define NB 2
#define NSEQ 2048
#define NTOK (NB*NSEQ)   // 4096

using short8  = __attribute__((ext_vector_type(8))) short;
using short4v = __attribute__((ext_vector_type(4))) short;
using f32x4   = __attribute__((ext_vector_type(4))) float;

#define INV_LN2 1.4426950408889634f

__device__ __forceinline__ short f2bf(float x) {
  __hip_bfloat16 h = __float2bfloat16(x);
  short s;
  __builtin_memcpy(&s, &h, 2);
  return s;
}

#define GLDS16(gp, lp) __builtin_amdgcn_global_load_lds( \
    (const __attribute__((address_space(1))) unsigned int*)(const void*)(gp), \
    (__attribute__((address_space(3))) unsigned int*)(void*)(lp), 16, 0, 0)

#define BAR() __builtin_amdgcn_s_barrier()
#define WAITVM(N) asm volatile("s_waitcnt vmcnt(" #N ")" ::: "memory")
#define PH_SYNC1() do { BAR(); \
    asm volatile("s_waitcnt lgkmcnt(0)" ::: "memory"); \
    __builtin_amdgcn_sched_barrier(0); \
    __builtin_amdgcn_s_setprio(1); } while (0)
#define PH_SYNC2() do { __builtin_amdgcn_s_setprio(0); BAR(); } while (0)

// ---------------- fused LayerNorm + weight cast ----------------
__global__ __launch_bounds__(256) void lncast_kernel(const float* __restrict__ x,
    const float* __restrict__ gamma, const float* __restrict__ beta, short* __restrict__ xn,
    const float* __restrict__ Wq, const float* __restrict__ Wk,
    const float* __restrict__ Wv, const float* __restrict__ Wo,
    short* __restrict__ wqb, short* __restrict__ wkb,
    short* __restrict__ wvb, short* __restrict__ wob) {
  const int bid = blockIdx.x;
  const int tid = threadIdx.x;
  if (bid < NTOK) {
    const float* xr = x + (size_t)bid * EMBED;
    float4 v = *(const float4*)(xr + tid * 4);
    float s  = v.x + v.y + v.z + v.w;
    float s2 = v.x*v.x + v.y*v.y + v.z*v.z + v.w*v.w;
#pragma unroll
    for (int off = 32; off; off >>= 1) {
      s  += __shfl_down(s, off);
      s2 += __shfl_down(s2, off);
    }
    __shared__ float red[8];
    const int wv = tid >> 6, ln = tid & 63;
    if (ln == 0) { red[wv] = s; red[4 + wv] = s2; }
    __syncthreads();
    s  = red[0] + red[1] + red[2] + red[3];
    s2 = red[4] + red[5] + red[6] + red[7];
    const float mu  = s * (1.0f / EMBED);
    const float var = s2 * (1.0f / EMBED) - mu * mu;
    const float inv = rsqrtf(var + 1e-5f);
    float4 g  = *(const float4*)(gamma + tid * 4);
    float4 bt = *(const float4*)(beta + tid * 4);
    short4v o;
    o[0] = f2bf((v.x - mu) * inv * g.x + bt.x);
    o[1] = f2bf((v.y - mu) * inv * g.y + bt.y);
    o[2] = f2bf((v.z - mu) * inv * g.z + bt.z);
    o[3] = f2bf((v.w - mu) * inv * g.w + bt.w);
    *(short4v*)(xn + (size_t)bid * EMBED + tid * 4) = o;
  } else {
    const int i = (bid - NTOK) * 1024 + tid * 4;
    const int wsel = i >> 20;
    const int off  = i & 1048575;
    const float* s = (wsel == 0) ? Wq : (wsel == 1) ? Wk : (wsel == 2) ? Wv : Wo;
    short* o       = (wsel == 0) ? wqb : (wsel == 1) ? wkb : (wsel == 2) ? wvb : wob;
    float4 v = *(const float4*)(s + off);
    short4v r;
    r[0] = f2bf(v.x); r[1] = f2bf(v.y); r[2] = f2bf(v.z); r[3] = f2bf(v.w);
    *(short4v*)(o + off) = r;
  }
}

// ---------------- QKV GEMM: 256x256, BK=64, 8 waves, m201-style 8-phase/2-K-tiles ----------------
// Merged N=3072 (Q|K|V). Grid 192 blocks (XCD-bijective swizzle), 1 block/CU.
__global__ __launch_bounds__(512, 2) void qkv8_kernel(
    const short* __restrict__ A,
    const short* __restrict__ W0, const short* __restrict__ W1, const short* __restrict__ W2,
    const float* __restrict__ b0, const float* __restrict__ b1, const float* __restrict__ b2,
    short* __restrict__ O0, short* __restrict__ O1, short* __restrict__ O2) {
  constexpr int K = 1024;
  const int orig = blockIdx.x;                 // 192 = 8 * 24, bijective XCD swizzle
  const int swzb = (orig & 7) * 24 + (orig >> 3);
  const int tn = swzb % 12, tm = swzb / 12;
  const int sel = tn >> 2;
  const short* Bw   = (sel == 0) ? W0 : (sel == 1) ? W1 : W2;
  const float* bias = (sel == 0) ? b0 : (sel == 1) ? b1 : b2;
  short* Cout       = (sel == 0) ? O0 : (sel == 1) ? O1 : O2;
  const int ncol0 = (tn & 3) * 256;

  const int tid = threadIdx.x;
  const int w = tid >> 6, lane = tid & 63;
  const int wr = w >> 2, wc = w & 3;           // 2(M) x 4(N) waves; per-wave 128x64
  const int g = lane >> 4, c = lane & 15;

  __shared__ short As[2][256 * 64];            // [m][k ^ ((m&7)<<3)] via pre-swizzled source
  __shared__ short Bs[2][256 * 64];            // [n][k ^ ((n&7)<<3)]

  f32x4 acc[8][4];
#pragma unroll
  for (int i = 0; i < 8; i++)
#pragma unroll
    for (int j = 0; j < 4; j++) acc[i][j] = (f32x4){0.f, 0.f, 0.f, 0.f};

  const int sr  = tid >> 3;                    // 0..63
  const int sc8 = (tid & 7) * 8;
  const int ssw = (sr & 7) << 3;
  const short* ga = A  + (size_t)(tm * 256) * K;
  const short* gb = Bw + (size_t)ncol0 * K;

  // A half h=0: rows {sr, 128+sr} (wr-mh0 rows); h=1: {64+sr, 192+sr} (mh1 rows).
  auto stA = [&](int buf, int h, int kt) {
#pragma unroll
    for (int i = 0; i < 2; i++) {
      const int row = h * 64 + i * 128 + sr;
      GLDS16(ga + (size_t)row * K + kt * 64 + (sc8 ^ ssw), &As[buf][row * 64 + sc8]);
    }
  };
  // B half h=0: cols 0..31 of each 64-col wave block; h=1: cols 32..63.
  auto stB = [&](int buf, int h, int kt) {
#pragma unroll
    for (int i = 0; i < 2; i++) {
      const int row = ((sr >> 5) + 2 * i) * 64 + (sr & 31) + h * 32;
      GLDS16(gb + (size_t)row * K + kt * 64 + (sc8 ^ ssw), &Bs[buf][row * 64 + sc8]);
    }
  };

  short8 af[4][2], bf[4][2];
  auto ldA = [&](const short* as, int mh) {
#pragma unroll
    for (int mi = 0; mi < 4; mi++) {
      const int row = wr * 128 + mh * 64 + mi * 16 + c;
      const int sw = (row & 7) << 3;
#pragma unroll
      for (int ks = 0; ks < 2; ks++)
        af[mi][ks] = *(const short8*)&as[row * 64 + ((ks * 32 + g * 8) ^ sw)];
    }
  };
  auto ldB = [&](const short* bs) {
#pragma unroll
    for (int ni = 0; ni < 4; ni++) {
      const int row = wc * 64 + ni * 16 + c;
      const int sw = (row & 7) << 3;
#pragma unroll
      for (int ks = 0; ks < 2; ks++)
        bf[ni][ks] = *(const short8*)&bs[row * 64 + ((ks * 32 + g * 8) ^ sw)];
    }
  };
  auto MF = [&](int mh, int nh) {
#pragma unroll
    for (int ks = 0; ks < 2; ks++)
#pragma unroll
      for (int mi = 0; mi < 4; mi++)
#pragma unroll
        for (int ni = 0; ni < 2; ni++)
          acc[mh * 4 + mi][nh * 2 + ni] = __builtin_amdgcn_mfma_f32_16x16x32_bf16(
              af[mi][ks], bf[nh * 2 + ni][ks], acc[mh * 4 + mi][nh * 2 + ni], 0, 0, 0);
  };

  // prologue: tile0 complete -> buf0; tile1 A',B0 -> buf1 (A''/B1 staged in ph0/ph1)
  stA(0, 0, 0); stB(0, 0, 0); stA(0, 1, 0); stB(0, 1, 0);
  stA(1, 0, 1); stB(1, 0, 1);
  WAITVM(4);                                   // 12 outstanding -> drain tile0 (8)
  BAR();

  for (int i = 0; i < 8; ++i) {
    const bool pre = (i < 7);
    const int e2 = 2 * i + 2, o1 = 2 * i + 1, o3 = 2 * i + 3;
    // ph0: read buf0 quadrant (0,*) A + all B; finish odd tile A''
    ldA(As[0], 0); ldB(Bs[0]);
    stA(1, 1, o1);
    PH_SYNC1(); MF(0, 0); PH_SYNC2();
    // ph1: finish odd tile B1
    stB(1, 1, o1);
    PH_SYNC1(); MF(0, 1); PH_SYNC2();
    // ph2: read A mh1; stage next-even A' (buf0 A' retired at ph1)
    ldA(As[0], 1);
    if (pre) stA(0, 0, e2);
    PH_SYNC1(); MF(1, 0); PH_SYNC2();
    // ph3: stage next-even B0; counted vmcnt drains odd tile before ph4 reads it
    if (pre) stB(0, 0, e2);
    PH_SYNC1(); MF(1, 1);
    __builtin_amdgcn_s_setprio(0);
    if (pre) { WAITVM(4); } else { WAITVM(0); }
    BAR();
    // ph4: read buf1 (odd tile); stage next-even A''
    ldA(As[1], 0); ldB(Bs[1]);
    if (pre) stA(0, 1, e2);
    PH_SYNC1(); MF(0, 0); PH_SYNC2();
    // ph5: stage next-even B1
    if (pre) stB(0, 1, e2);
    PH_SYNC1(); MF(0, 1); PH_SYNC2();
    // ph6: read A mh1 (buf1); stage next-odd A'
    ldA(As[1], 1);
    if (pre) stA(1, 0, o3);
    PH_SYNC1(); MF(1, 0); PH_SYNC2();
    // ph7: stage next-odd B0; counted vmcnt drains next-even tile before next ph0
    if (pre) stB(1, 0, o3);
    PH_SYNC1(); MF(1, 1);
    __builtin_amdgcn_s_setprio(0);
    if (pre) WAITVM(4);
    BAR();
  }

  // epilogue: bias + bf16 store (mapping verified in round 5)
#pragma unroll
  for (int ni4 = 0; ni4 < 4; ni4++) {
    const int lcol = ncol0 + wc * 64 + ni4 * 16 + c;
    const float bsv = bias[lcol];
#pragma unroll
    for (int mi8 = 0; mi8 < 8; mi8++) {
      const int mo = (mi8 >> 2) * 64 + (mi8 & 3) * 16;
      const int row = tm * 256 + wr * 128 + mo + g * 4;
#pragma unroll
      for (int j = 0; j < 4; j++)
        Cout[(size_t)(row + j) * 1024 + lcol] = f2bf(acc[mi8][ni4][j] + bsv);
    }
  }
}

// ---------------- GEMM (proj): C[M][1024] = A[M][1024] @ W^T + bias ----------------
template<bool F32OUT>
__global__ __launch_bounds__(256) void gemm_kernel(
    const short* __restrict__ A, const short* __restrict__ Bw,
    const float* __restrict__ bias, void* __restrict__ Cout) {
  constexpr int K = 1024, NOUT = 1024;
  const int tn = blockIdx.x, tm = blockIdx.y;
  const int tid = threadIdx.x, w = tid >> 6, lane = tid & 63;
  const int wm = w >> 1, wn = w & 1;
  const int g = lane >> 4, c = lane & 15;

  __shared__ short As[128 * 32];
  __shared__ short Bs[128 * 32];

  f32x4 acc[4][4];
#pragma unroll
  for (int i = 0; i < 4; i++)
#pragma unroll
    for (int j = 0; j < 4; j++) acc[i][j] = (f32x4){0.f, 0.f, 0.f, 0.f};

  const int crow = tid >> 2;
  const int ckc  = tid & 3;
  const short* ga = A  + (size_t)(tm * 128 + crow) * K + ckc * 8;
  const short* gb = Bw + (size_t)(tn * 128 + crow) * K + ckc * 8;
  short* la = &As[tid * 8];
  short* lb = &Bs[tid * 8];

  for (int k0 = 0; k0 < K; k0 += 32) {
    __syncthreads();
    GLDS16(ga + k0, la);
    GLDS16(ga + k0 + (size_t)64 * K, la + 64 * 32);
    GLDS16(gb + k0, lb);
    GLDS16(gb + k0 + (size_t)64 * K, lb + 64 * 32);
    __syncthreads();
    short8 af[4], bfr[4];
#pragma unroll
    for (int mi = 0; mi < 4; mi++)
      af[mi] = *(const short8*)&As[(wm * 64 + mi * 16 + c) * 32 + g * 8];
#pragma unroll
    for (int ni = 0; ni < 4; ni++)
      bfr[ni] = *(const short8*)&Bs[(wn * 64 + ni * 16 + c) * 32 + g * 8];
#pragma unroll
    for (int mi = 0; mi < 4; mi++)
#pragma unroll
      for (int ni = 0; ni < 4; ni++)
        acc[mi][ni] = __builtin_amdgcn_mfma_f32_16x16x32_bf16(af[mi], bfr[ni], acc[mi][ni], 0, 0, 0);
  }

#pragma unroll
  for (int ni = 0; ni < 4; ni++) {
    const int col = tn * 128 + wn * 64 + ni * 16 + c;
    const float bs = bias[col];
#pragma unroll
    for (int mi = 0; mi < 4; mi++) {
#pragma unroll
      for (int j = 0; j < 4; j++) {
        const int row = tm * 128 + wm * 64 + mi * 16 + g * 4 + j;
        const float v = acc[mi][ni][j] + bs;
        if constexpr (F32OUT)
          ((float*)Cout)[(size_t)row * NOUT + col] = v;
        else
          ((short*)Cout)[(size_t)row * NOUT + col] = f2bf(v);
      }
    }
  }
}

// ---------------- V transpose: [n][h*64+d] -> [b][h][d][n(2048)] ----------------
__global__ __launch_bounds__(256) void vtrans_kernel(const short* __restrict__ vb,
                                                     short* __restrict__ vt) {
  const int n0 = blockIdx.x * 64;
  const int bh = blockIdx.y;
  const int b = bh >> 4, h = bh & 15;
  const int tid = threadIdx.x;
  __shared__ short tl[64 * 68];

  const int r  = tid >> 3;
  const int c8 = (tid & 7) * 8;
#pragma unroll
  for (int i = 0; i < 2; i++) {
    const int row = r + i * 32;
    short8 v = *(const short8*)(vb + (size_t)(b * NSEQ + n0 + row) * EMBED + h * 64 + c8);
    *(short8*)&tl[row * 68 + c8] = v;
  }
  __syncthreads();
  const int d  = tid >> 2;
  const int ns = (tid & 3) * 16;
  short8 o0, o1;
#pragma unroll
  for (int e = 0; e < 8; e++) {
    o0[e] = tl[(ns + e) * 68 + d];
    o1[e] = tl[(ns + 8 + e) * 68 + d];
  }
  short* dst = vt + ((size_t)((b * 16 + h) * 64 + d)) * 2048 + n0 + ns;
  *(short8*)dst = o0;
  *(short8*)(dst + 8) = o1;
}

// ---------------- Flash attention: 8 waves x 16 q-rows, bias folded into MFMA ----------------
__global__ __launch_bounds__(512, 4) void attn_kernel(
    const short* __restrict__ Qm, const short* __restrict__ Km, const short* __restrict__ Vt,
    const float* __restrict__ relb, short* __restrict__ ctx) {
  const int bid = blockIdx.x;
  const int bh  = bid & 31;
  const int idx = bid >> 5;
  const int qpair = (idx < 8) ? (15 - idx) : (idx - 8);
  const int b = bh >> 4, h = bh & 15;
  const int tid = threadIdx.x, w = tid >> 6, lane = tid & 63;
  const int g = lane >> 4, c = lane & 15;
  constexpr float S31 = 31.0f / 2047.0f;
  constexpr float CSC = 0.125f * INV_LN2;

  __shared__ short k_lds[2][64 * 64];
  __shared__ short vt_lds[2][64 * 64];
  __shared__ short p_lds[8][16 * 64];
  __shared__ short rbf[128 * 32];
  __shared__ short u_lds[2][64 * 40];

  const int qbase = qpair * 128;
  const size_t bhq = (size_t)b * NSEQ * EMBED + h * HDIM;
  const short* vtb = Vt + (size_t)((b << 4) + h) * 64 * 2048;

  short8 qf[2];
  {
    const short* qp = Qm + bhq + (size_t)(qbase + w * 16 + c) * EMBED;
    qf[0] = *(const short8*)(qp + g * 8);
    qf[1] = *(const short8*)(qp + 32 + g * 8);
  }

  const int srow = tid >> 3;
  const int sd0  = (tid & 7) * 8;
  const int swz  = (srow & 7) << 3;

  auto buildU = [&](int buf, int kv) {
    if (tid < 64) {
      short* ur = &u_lds[buf][tid * 40];
      *(int4*)&ur[0]  = (int4){0, 0, 0, 0};
      *(int4*)&ur[8]  = (int4){0, 0, 0, 0};
      *(int4*)&ur[16] = (int4){0, 0, 0, 0};
      *(int4*)&ur[24] = (int4){0, 0, 0, 0};
      const int m = kv + tid;
      if (m != NSEQ - 1) {
        const float pos = m * S31;
        const int i0 = (int)pos;
        const float fr = pos - (float)i0;
        ur[i0]     = f2bf(1.0f - fr);
        ur[i0 + 1] = f2bf(fr);
      }
    }
  };

  GLDS16(Km + bhq + (size_t)srow * EMBED + (sd0 ^ swz), &k_lds[0][srow * 64 + sd0]);
  GLDS16(vtb + (size_t)srow * 2048 + (sd0 ^ swz),       &vt_lds[0][srow * 64 + sd0]);
  for (int i = tid; i < 128 * 32; i += 512) {
    const int qr = i >> 5, jj = i & 31;
    const int qg0 = qbase + qr;
    float rv = 0.f;
    if (qg0 != NSEQ - 1) {
      const float pos = qg0 * S31;
      const int i0 = (int)pos;
      const int i1 = min(i0 + 1, 31);
      const float fr = pos - (float)i0;
      const float* T = relb + h * 1024;
      rv = ((1.f - fr) * T[i0 * 32 + jj] + fr * T[i1 * 32 + jj]) * 8.0f;
    }
    rbf[i] = f2bf(rv);
  }
  buildU(0, 0);
  __syncthreads();

  const short8 rq = *(const short8*)&rbf[(w * 16 + c) * 32 + g * 8];

  float mrow = -3.0e38f, lrow = 0.f;
  f32x4 oacc[4];
#pragma unroll
  for (int db = 0; db < 4; db++) oacc[db] = (f32x4){0.f, 0.f, 0.f, 0.f};

  const int qg  = qbase + w * 16 + c;
  const int qhi = qbase + w * 16 + 15;
  const int csw = (c & 7) << 3;
  const int nkv = 2 * qpair + 2;

  for (int kt = 0; kt < nkv; kt++) {
    const int cur = kt & 1;
    const int kv0 = kt * 64;

    if (kt + 1 < nkv) {
      GLDS16(Km + bhq + (size_t)(kv0 + 64 + srow) * EMBED + (sd0 ^ swz),
             &k_lds[cur ^ 1][srow * 64 + sd0]);
      GLDS16(vtb + (size_t)srow * 2048 + (kv0 + 64) + (sd0 ^ swz),
             &vt_lds[cur ^ 1][srow * 64 + sd0]);
      buildU(cur ^ 1, kv0 + 64);
    }

    if (kv0 <= qhi) {
      const short* kl = &k_lds[cur][0];
      const short* vl = &vt_lds[cur][0];
      const short* ul = &u_lds[cur][0];

      f32x4 st[4];
#pragma unroll
      for (int mb = 0; mb < 4; mb++) st[mb] = (f32x4){0.f, 0.f, 0.f, 0.f};
      __builtin_amdgcn_s_setprio(1);
#pragma unroll
      for (int kh = 0; kh < 2; kh++) {
        const int dk = kh * 32 + g * 8;
#pragma unroll
        for (int mb = 0; mb < 4; mb++) {
          const int row = mb * 16 + c;
          short8 kf = *(const short8*)&kl[row * 64 + (dk ^ ((row & 7) << 3))];
          st[mb] = __builtin_amdgcn_mfma_f32_16x16x32_bf16(kf, qf[kh], st[mb], 0, 0, 0);
        }
      }
#pragma unroll
      for (int mb = 0; mb < 4; mb++) {
        short8 uf = *(const short8*)&ul[(mb * 16 + c) * 40 + g * 8];
        st[mb] = __builtin_amdgcn_mfma_f32_16x16x32_bf16(uf, rq, st[mb], 0, 0, 0);
      }
      __builtin_amdgcn_s_setprio(0);

      const bool diag = (kv0 + 63 > qg);
      if (diag) {
#pragma unroll
        for (int mb = 0; mb < 4; mb++)
#pragma unroll
          for (int j = 0; j < 4; j++) {
            const int mg = kv0 + mb * 16 + g * 4 + j;
            if (mg > qg) st[mb][j] = -1.0e38f;
          }
      }
      float pmr = -3.0e38f;
#pragma unroll
      for (int mb = 0; mb < 4; mb++)
#pragma unroll
        for (int j = 0; j < 4; j++) pmr = fmaxf(pmr, st[mb][j]);
      float pmax = pmr * CSC;
      pmax = fmaxf(pmax, __shfl_xor(pmax, 16));
      pmax = fmaxf(pmax, __shfl_xor(pmax, 32));

      if (!__all(pmax - mrow <= 11.6f)) {
        const float mnew = fmaxf(mrow, pmax);
        const float al = exp2f(mrow - mnew);
        mrow = mnew;
        lrow *= al;
        float alj[4];
#pragma unroll
        for (int j = 0; j < 4; j++) alj[j] = __shfl(al, g * 4 + j);
#pragma unroll
        for (int db = 0; db < 4; db++)
#pragma unroll
          for (int j = 0; j < 4; j++) oacc[db][j] *= alj[j];
      }

      float p[4][4];
      float rs = 0.f;
#pragma unroll
      for (int mb = 0; mb < 4; mb++)
#pragma unroll
        for (int j = 0; j < 4; j++) {
          const float pe = exp2f(fmaf(st[mb][j], CSC, -mrow));
          p[mb][j] = pe;
          rs += pe;
        }
      rs += __shfl_xor(rs, 16);
      rs += __shfl_xor(rs, 32);
      lrow += rs;

      short* pw = &p_lds[w][0];
#pragma unroll
      for (int mb = 0; mb < 4; mb++)
#pragma unroll
        for (int jh = 0; jh < 2; jh++) {
          const int m = mb * 16 + g * 4 + jh * 2;
          unsigned int pk = ((unsigned int)(unsigned short)f2bf(p[mb][jh * 2 + 1]) << 16)
                          |  (unsigned int)(unsigned short)f2bf(p[mb][jh * 2]);
          *(unsigned int*)&pw[c * 64 + (m ^ csw)] = pk;
        }

      __builtin_amdgcn_s_setprio(1);
#pragma unroll
      for (int kb = 0; kb < 2; kb++) {
        const int m0 = kb * 32 + g * 8;
        short8 pa = *(const short8*)&pw[c * 64 + (m0 ^ csw)];
#pragma unroll
        for (int db = 0; db < 4; db++) {
          const int d = db * 16 + c;
          short8 vf = *(const short8*)&vl[d * 64 + (m0 ^ ((d & 7) << 3))];
          oacc[db] = __builtin_amdgcn_mfma_f32_16x16x32_bf16(pa, vf, oacc[db], 0, 0, 0);
        }
      }
      __builtin_amdgcn_s_setprio(0);
    }
    __syncthreads();
  }

  float linv[4];
#pragma unroll
  for (int j = 0; j < 4; j++) linv[j] = 1.f / __shfl(lrow, g * 4 + j);
#pragma unroll
  for (int j = 0; j < 4; j++) {
    short* op = ctx + bhq + (size_t)(qbase + w * 16 + g * 4 + j) * EMBED;
#pragma unroll
    for (int db = 0; db < 4; db++)
      op[db * 16 + c] = f2bf(oacc[db][j] * linv[j]);
  }
}

extern "C" void kernel_launch(void* const* d_in, const int* in_sizes, int n_in,
                              void* d_out, int out_size, void* d_ws, size_t ws_size,
                              hipStream_t stream) {
  const float* x     = (const float*)d_in[0];
  const float* Wq    = (const float*)d_in[1];
  const float* bq    = (const float*)d_in[2];
  const float* Wk    = (const float*)d_in[3];
  const float* bk    = (const float*)d_in[4];
  const float* Wv    = (const float*)d_in[5];
  const float* bv    = (const float*)d_in[6];
  const float* Wo    = (const float*)d_in[7];
  const float* bo    = (const float*)d_in[8];
  const float* gamma = (const float*)d_in[9];
  const float* beta  = (const float*)d_in[10];
  const float* relb  = (const float*)d_in[11];
  float* out = (float*)d_out;

  char* ws = (char*)d_ws;
  short* xn  = (short*)ws; ws += (size_t)NTOK * EMBED * 2;   // reused as vtb after QKV GEMM
  short* wqb = (short*)ws; ws += (size_t)EMBED * EMBED * 2;
  short* wkb = (short*)ws; ws += (size_t)EMBED * EMBED * 2;
  short* wvb = (short*)ws; ws += (size_t)EMBED * EMBED * 2;
  short* wob = (short*)ws; ws += (size_t)EMBED * EMBED * 2;
  short* qb  = (short*)ws; ws += (size_t)NTOK * EMBED * 2;
  short* kb_ = (short*)ws; ws += (size_t)NTOK * EMBED * 2;
  short* vb  = (short*)ws; ws += (size_t)NTOK * EMBED * 2;
  short* ctx = (short*)ws; ws += (size_t)NTOK * EMBED * 2;
  short* vtb = xn;

  lncast_kernel<<<dim3(NTOK + 4096), dim3(256), 0, stream>>>(
      x, gamma, beta, xn, Wq, Wk, Wv, Wo, wqb, wkb, wvb, wob);
  qkv8_kernel<<<dim3(192), dim3(512), 0, stream>>>(
      xn, wqb, wkb, wvb, bq, bk, bv, qb, kb_, vb);
  vtrans_kernel<<<dim3(32, 32), dim3(256), 0, stream>>>(vb, vtb);
  attn_kernel<<<dim3(512), dim3(512), 0, stream>>>(qb, kb_, vtb, relb, ctx);
  gemm_kernel<true><<<dim3(8, 32), dim3(256), 0, stream>>>(ctx, wob, bo, (void*)out);
}

// Round 8
// 211.466 us; speedup vs baseline: 1.1421x; 1.0101x over previous
//
#include <hip/hip_runtime.h>
#include <hip/hip_bf16.h>

#define EMBED 1024
#define NHEADS 16
#define HDIM 64
#define NB 2
#define NSEQ 2048
#define NTOK (NB*NSEQ)   // 4096

using short8  = __attribute__((ext_vector_type(8))) short;
using short4v = __attribute__((ext_vector_type(4))) short;
using f32x4   = __attribute__((ext_vector_type(4))) float;

#define INV_LN2 1.4426950408889634f

__device__ __forceinline__ short f2bf(float x) {
  __hip_bfloat16 h = __float2bfloat16(x);
  short s;
  __builtin_memcpy(&s, &h, 2);
  return s;
}

#define GLDS16(gp, lp) __builtin_amdgcn_global_load_lds( \
    (const __attribute__((address_space(1))) unsigned int*)(const void*)(gp), \
    (__attribute__((address_space(3))) unsigned int*)(void*)(lp), 16, 0, 0)

// ---------------- fused LayerNorm + weight cast ----------------
__global__ __launch_bounds__(256) void lncast_kernel(const float* __restrict__ x,
    const float* __restrict__ gamma, const float* __restrict__ beta, short* __restrict__ xn,
    const float* __restrict__ Wq, const float* __restrict__ Wk,
    const float* __restrict__ Wv, const float* __restrict__ Wo,
    short* __restrict__ wqb, short* __restrict__ wkb,
    short* __restrict__ wvb, short* __restrict__ wob) {
  const int bid = blockIdx.x;
  const int tid = threadIdx.x;
  if (bid < NTOK) {
    const float* xr = x + (size_t)bid * EMBED;
    float4 v = *(const float4*)(xr + tid * 4);
    float s  = v.x + v.y + v.z + v.w;
    float s2 = v.x*v.x + v.y*v.y + v.z*v.z + v.w*v.w;
#pragma unroll
    for (int off = 32; off; off >>= 1) {
      s  += __shfl_down(s, off);
      s2 += __shfl_down(s2, off);
    }
    __shared__ float red[8];
    const int wv = tid >> 6, ln = tid & 63;
    if (ln == 0) { red[wv] = s; red[4 + wv] = s2; }
    __syncthreads();
    s  = red[0] + red[1] + red[2] + red[3];
    s2 = red[4] + red[5] + red[6] + red[7];
    const float mu  = s * (1.0f / EMBED);
    const float var = s2 * (1.0f / EMBED) - mu * mu;
    const float inv = rsqrtf(var + 1e-5f);
    float4 g  = *(const float4*)(gamma + tid * 4);
    float4 bt = *(const float4*)(beta + tid * 4);
    short4v o;
    o[0] = f2bf((v.x - mu) * inv * g.x + bt.x);
    o[1] = f2bf((v.y - mu) * inv * g.y + bt.y);
    o[2] = f2bf((v.z - mu) * inv * g.z + bt.z);
    o[3] = f2bf((v.w - mu) * inv * g.w + bt.w);
    *(short4v*)(xn + (size_t)bid * EMBED + tid * 4) = o;
  } else {
    const int i = (bid - NTOK) * 1024 + tid * 4;
    const int wsel = i >> 20;
    const int off  = i & 1048575;
    const float* s = (wsel == 0) ? Wq : (wsel == 1) ? Wk : (wsel == 2) ? Wv : Wo;
    short* o       = (wsel == 0) ? wqb : (wsel == 1) ? wkb : (wsel == 2) ? wvb : wob;
    float4 v = *(const float4*)(s + off);
    short4v r;
    r[0] = f2bf(v.x); r[1] = f2bf(v.y); r[2] = f2bf(v.z); r[3] = f2bf(v.w);
    *(short4v*)(o + off) = r;
  }
}

// ---------------- QKV GEMM: 128x192 tile, BK=64, 8 waves, 2-phase dbuf ----------------
// Wcat = wqb (wqb|wkb|wvb contiguous). Grid 512 blocks (2/CU), XCD-bijective swizzle.
__global__ __launch_bounds__(512, 4) void qkv2ph_kernel(
    const short* __restrict__ A, const short* __restrict__ Wcat,
    const float* __restrict__ b0, const float* __restrict__ b1, const float* __restrict__ b2,
    short* __restrict__ O0, short* __restrict__ O1, short* __restrict__ O2) {
  constexpr int K = 1024;
  const int orig = blockIdx.x;                  // 512 = 8 * 64, bijective XCD swizzle
  const int swzb = (orig & 7) * 64 + (orig >> 3);
  const int tn = swzb & 15, tm = swzb >> 4;

  const int tid = threadIdx.x;
  const int w = tid >> 6, lane = tid & 63;
  const int wr = w >> 2, wc = w & 3;            // 2(M) x 4(N); per-wave 64x48
  const int g = lane >> 4, c = lane & 15;

  __shared__ short As[2][128 * 64];             // [m][k ^ ((m&7)<<3)] via pre-swizzled source
  __shared__ short Bs[2][192 * 64];             // [n][k ^ ((n&7)<<3)]

  f32x4 acc[4][3];
#pragma unroll
  for (int i = 0; i < 4; i++)
#pragma unroll
    for (int j = 0; j < 3; j++) acc[i][j] = (f32x4){0.f, 0.f, 0.f, 0.f};

  const int sr  = tid >> 3;                     // 0..63
  const int sc8 = (tid & 7) * 8;
  const int ssw = (sr & 7) << 3;
  const short* ga = A    + (size_t)(tm * 128) * K;
  const short* gb = Wcat + (size_t)(tn * 192) * K;

  auto STAGE = [&](int buf, int kt) {
#pragma unroll
    for (int u = 0; u < 2; u++) {
      const int row = u * 64 + sr;
      GLDS16(ga + (size_t)row * K + kt * 64 + (sc8 ^ ssw), &As[buf][row * 64 + sc8]);
    }
#pragma unroll
    for (int u = 0; u < 3; u++) {
      const int row = u * 64 + sr;
      GLDS16(gb + (size_t)row * K + kt * 64 + (sc8 ^ ssw), &Bs[buf][row * 64 + sc8]);
    }
  };

  STAGE(0, 0);
  __syncthreads();

  for (int kt = 0; kt < 16; ++kt) {
    const int cur = kt & 1;
    if (kt + 1 < 16) STAGE(cur ^ 1, kt + 1);
    const short* as = As[cur];
    const short* bs = Bs[cur];
#pragma unroll
    for (int ks = 0; ks < 2; ks++) {
      short8 af[4], bf[3];
#pragma unroll
      for (int mi = 0; mi < 4; mi++) {
        const int row = wr * 64 + mi * 16 + c;
        af[mi] = *(const short8*)&as[row * 64 + ((ks * 32 + g * 8) ^ ((row & 7) << 3))];
      }
#pragma unroll
      for (int ni = 0; ni < 3; ni++) {
        const int row = wc * 48 + ni * 16 + c;
        bf[ni] = *(const short8*)&bs[row * 64 + ((ks * 32 + g * 8) ^ ((row & 7) << 3))];
      }
      __builtin_amdgcn_s_setprio(1);
#pragma unroll
      for (int mi = 0; mi < 4; mi++)
#pragma unroll
        for (int ni = 0; ni < 3; ni++)
          acc[mi][ni] = __builtin_amdgcn_mfma_f32_16x16x32_bf16(af[mi], bf[ni], acc[mi][ni], 0, 0, 0);
      __builtin_amdgcn_s_setprio(0);
    }
    __syncthreads();
  }

  // epilogue: per-16-col group select Q/K/V buffer (groups are 16-aligned, never span 1024)
#pragma unroll
  for (int ni = 0; ni < 3; ni++) {
    const int col = tn * 192 + wc * 48 + ni * 16 + c;
    const int sel = col >> 10, lc = col & 1023;
    short* O        = (sel == 0) ? O0 : (sel == 1) ? O1 : O2;
    const float* bb = (sel == 0) ? b0 : (sel == 1) ? b1 : b2;
    const float bsv = bb[lc];
#pragma unroll
    for (int mi = 0; mi < 4; mi++) {
      const int row = tm * 128 + wr * 64 + mi * 16 + g * 4;
#pragma unroll
      for (int j = 0; j < 4; j++)
        O[(size_t)(row + j) * 1024 + lc] = f2bf(acc[mi][ni][j] + bsv);
    }
  }
}

// ---------------- GEMM (proj): C[M][1024] = A[M][1024] @ W^T + bias ----------------
template<bool F32OUT>
__global__ __launch_bounds__(256) void gemm_kernel(
    const short* __restrict__ A, const short* __restrict__ Bw,
    const float* __restrict__ bias, void* __restrict__ Cout) {
  constexpr int K = 1024, NOUT = 1024;
  const int tn = blockIdx.x, tm = blockIdx.y;
  const int tid = threadIdx.x, w = tid >> 6, lane = tid & 63;
  const int wm = w >> 1, wn = w & 1;
  const int g = lane >> 4, c = lane & 15;

  __shared__ short As[128 * 32];
  __shared__ short Bs[128 * 32];

  f32x4 acc[4][4];
#pragma unroll
  for (int i = 0; i < 4; i++)
#pragma unroll
    for (int j = 0; j < 4; j++) acc[i][j] = (f32x4){0.f, 0.f, 0.f, 0.f};

  const int crow = tid >> 2;
  const int ckc  = tid & 3;
  const short* ga = A  + (size_t)(tm * 128 + crow) * K + ckc * 8;
  const short* gb = Bw + (size_t)(tn * 128 + crow) * K + ckc * 8;
  short* la = &As[tid * 8];
  short* lb = &Bs[tid * 8];

  for (int k0 = 0; k0 < K; k0 += 32) {
    __syncthreads();
    GLDS16(ga + k0, la);
    GLDS16(ga + k0 + (size_t)64 * K, la + 64 * 32);
    GLDS16(gb + k0, lb);
    GLDS16(gb + k0 + (size_t)64 * K, lb + 64 * 32);
    __syncthreads();
    short8 af[4], bfr[4];
#pragma unroll
    for (int mi = 0; mi < 4; mi++)
      af[mi] = *(const short8*)&As[(wm * 64 + mi * 16 + c) * 32 + g * 8];
#pragma unroll
    for (int ni = 0; ni < 4; ni++)
      bfr[ni] = *(const short8*)&Bs[(wn * 64 + ni * 16 + c) * 32 + g * 8];
#pragma unroll
    for (int mi = 0; mi < 4; mi++)
#pragma unroll
      for (int ni = 0; ni < 4; ni++)
        acc[mi][ni] = __builtin_amdgcn_mfma_f32_16x16x32_bf16(af[mi], bfr[ni], acc[mi][ni], 0, 0, 0);
  }

#pragma unroll
  for (int ni = 0; ni < 4; ni++) {
    const int col = tn * 128 + wn * 64 + ni * 16 + c;
    const float bs = bias[col];
#pragma unroll
    for (int mi = 0; mi < 4; mi++) {
#pragma unroll
      for (int j = 0; j < 4; j++) {
        const int row = tm * 128 + wm * 64 + mi * 16 + g * 4 + j;
        const float v = acc[mi][ni][j] + bs;
        if constexpr (F32OUT)
          ((float*)Cout)[(size_t)row * NOUT + col] = v;
        else
          ((short*)Cout)[(size_t)row * NOUT + col] = f2bf(v);
      }
    }
  }
}

// ---------------- V transpose: [n][h*64+d] -> [b][h][d][n(2048)] ----------------
__global__ __launch_bounds__(256) void vtrans_kernel(const short* __restrict__ vb,
                                                     short* __restrict__ vt) {
  const int n0 = blockIdx.x * 64;
  const int bh = blockIdx.y;
  const int b = bh >> 4, h = bh & 15;
  const int tid = threadIdx.x;
  __shared__ short tl[64 * 68];

  const int r  = tid >> 3;
  const int c8 = (tid & 7) * 8;
#pragma unroll
  for (int i = 0; i < 2; i++) {
    const int row = r + i * 32;
    short8 v = *(const short8*)(vb + (size_t)(b * NSEQ + n0 + row) * EMBED + h * 64 + c8);
    *(short8*)&tl[row * 68 + c8] = v;
  }
  __syncthreads();
  const int d  = tid >> 2;
  const int ns = (tid & 3) * 16;
  short8 o0, o1;
#pragma unroll
  for (int e = 0; e < 8; e++) {
    o0[e] = tl[(ns + e) * 68 + d];
    o1[e] = tl[(ns + 8 + e) * 68 + d];
  }
  short* dst = vt + ((size_t)((b * 16 + h) * 64 + d)) * 2048 + n0 + ns;
  *(short8*)dst = o0;
  *(short8*)(dst + 8) = o1;
}

// ---------------- Flash attention: 8 waves x 16 q-rows, bias folded into MFMA ----------------
__global__ __launch_bounds__(512, 4) void attn_kernel(
    const short* __restrict__ Qm, const short* __restrict__ Km, const short* __restrict__ Vt,
    const float* __restrict__ relb, short* __restrict__ ctx) {
  const int bid = blockIdx.x;
  const int bh  = bid & 31;
  const int idx = bid >> 5;
  const int qpair = (idx < 8) ? (15 - idx) : (idx - 8);
  const int b = bh >> 4, h = bh & 15;
  const int tid = threadIdx.x, w = tid >> 6, lane = tid & 63;
  const int g = lane >> 4, c = lane & 15;
  constexpr float S31 = 31.0f / 2047.0f;
  constexpr float CSC = 0.125f * INV_LN2;

  __shared__ short k_lds[2][64 * 64];
  __shared__ short vt_lds[2][64 * 64];
  __shared__ short p_lds[8][16 * 64];
  __shared__ short rbf[128 * 32];
  __shared__ short u_lds[2][64 * 40];

  const int qbase = qpair * 128;
  const size_t bhq = (size_t)b * NSEQ * EMBED + h * HDIM;
  const short* vtb = Vt + (size_t)((b << 4) + h) * 64 * 2048;

  short8 qf[2];
  {
    const short* qp = Qm + bhq + (size_t)(qbase + w * 16 + c) * EMBED;
    qf[0] = *(const short8*)(qp + g * 8);
    qf[1] = *(const short8*)(qp + 32 + g * 8);
  }

  const int srow = tid >> 3;
  const int sd0  = (tid & 7) * 8;
  const int swz  = (srow & 7) << 3;

  auto buildU = [&](int buf, int kv) {
    if (tid < 64) {
      short* ur = &u_lds[buf][tid * 40];
      *(int4*)&ur[0]  = (int4){0, 0, 0, 0};
      *(int4*)&ur[8]  = (int4){0, 0, 0, 0};
      *(int4*)&ur[16] = (int4){0, 0, 0, 0};
      *(int4*)&ur[24] = (int4){0, 0, 0, 0};
      const int m = kv + tid;
      if (m != NSEQ - 1) {
        const float pos = m * S31;
        const int i0 = (int)pos;
        const float fr = pos - (float)i0;
        ur[i0]     = f2bf(1.0f - fr);
        ur[i0 + 1] = f2bf(fr);
      }
    }
  };

  GLDS16(Km + bhq + (size_t)srow * EMBED + (sd0 ^ swz), &k_lds[0][srow * 64 + sd0]);
  GLDS16(vtb + (size_t)srow * 2048 + (sd0 ^ swz),       &vt_lds[0][srow * 64 + sd0]);
  for (int i = tid; i < 128 * 32; i += 512) {
    const int qr = i >> 5, jj = i & 31;
    const int qg0 = qbase + qr;
    float rv = 0.f;
    if (qg0 != NSEQ - 1) {
      const float pos = qg0 * S31;
      const int i0 = (int)pos;
      const int i1 = min(i0 + 1, 31);
      const float fr = pos - (float)i0;
      const float* T = relb + h * 1024;
      rv = ((1.f - fr) * T[i0 * 32 + jj] + fr * T[i1 * 32 + jj]) * 8.0f;
    }
    rbf[i] = f2bf(rv);
  }
  buildU(0, 0);
  __syncthreads();

  const short8 rq = *(const short8*)&rbf[(w * 16 + c) * 32 + g * 8];

  float mrow = -3.0e38f, lrow = 0.f;
  f32x4 oacc[4];
#pragma unroll
  for (int db = 0; db < 4; db++) oacc[db] = (f32x4){0.f, 0.f, 0.f, 0.f};

  const int qg  = qbase + w * 16 + c;
  const int qhi = qbase + w * 16 + 15;
  const int csw = (c & 7) << 3;
  const int nkv = 2 * qpair + 2;

  for (int kt = 0; kt < nkv; kt++) {
    const int cur = kt & 1;
    const int kv0 = kt * 64;

    if (kt + 1 < nkv) {
      GLDS16(Km + bhq + (size_t)(kv0 + 64 + srow) * EMBED + (sd0 ^ swz),
             &k_lds[cur ^ 1][srow * 64 + sd0]);
      GLDS16(vtb + (size_t)srow * 2048 + (kv0 + 64) + (sd0 ^ swz),
             &vt_lds[cur ^ 1][srow * 64 + sd0]);
      buildU(cur ^ 1, kv0 + 64);
    }

    if (kv0 <= qhi) {
      const short* kl = &k_lds[cur][0];
      const short* vl = &vt_lds[cur][0];
      const short* ul = &u_lds[cur][0];

      f32x4 st[4];
#pragma unroll
      for (int mb = 0; mb < 4; mb++) st[mb] = (f32x4){0.f, 0.f, 0.f, 0.f};
      __builtin_amdgcn_s_setprio(1);
#pragma unroll
      for (int kh = 0; kh < 2; kh++) {
        const int dk = kh * 32 + g * 8;
#pragma unroll
        for (int mb = 0; mb < 4; mb++) {
          const int row = mb * 16 + c;
          short8 kf = *(const short8*)&kl[row * 64 + (dk ^ ((row & 7) << 3))];
          st[mb] = __builtin_amdgcn_mfma_f32_16x16x32_bf16(kf, qf[kh], st[mb], 0, 0, 0);
        }
      }
#pragma unroll
      for (int mb = 0; mb < 4; mb++) {
        short8 uf = *(const short8*)&ul[(mb * 16 + c) * 40 + g * 8];
        st[mb] = __builtin_amdgcn_mfma_f32_16x16x32_bf16(uf, rq, st[mb], 0, 0, 0);
      }
      __builtin_amdgcn_s_setprio(0);

      const bool diag = (kv0 + 63 > qg);
      if (diag) {
#pragma unroll
        for (int mb = 0; mb < 4; mb++)
#pragma unroll
          for (int j = 0; j < 4; j++) {
            const int mg = kv0 + mb * 16 + g * 4 + j;
            if (mg > qg) st[mb][j] = -1.0e38f;
          }
      }
      float pmr = -3.0e38f;
#pragma unroll
      for (int mb = 0; mb < 4; mb++)
#pragma unroll
        for (int j = 0; j < 4; j++) pmr = fmaxf(pmr, st[mb][j]);
      float pmax = pmr * CSC;
      pmax = fmaxf(pmax, __shfl_xor(pmax, 16));
      pmax = fmaxf(pmax, __shfl_xor(pmax, 32));

      if (!__all(pmax - mrow <= 11.6f)) {
        const float mnew = fmaxf(mrow, pmax);
        const float al = exp2f(mrow - mnew);
        mrow = mnew;
        lrow *= al;
        float alj[4];
#pragma unroll
        for (int j = 0; j < 4; j++) alj[j] = __shfl(al, g * 4 + j);
#pragma unroll
        for (int db = 0; db < 4; db++)
#pragma unroll
          for (int j = 0; j < 4; j++) oacc[db][j] *= alj[j];
      }

      float p[4][4];
      float rs = 0.f;
#pragma unroll
      for (int mb = 0; mb < 4; mb++)
#pragma unroll
        for (int j = 0; j < 4; j++) {
          const float pe = exp2f(fmaf(st[mb][j], CSC, -mrow));
          p[mb][j] = pe;
          rs += pe;
        }
      rs += __shfl_xor(rs, 16);
      rs += __shfl_xor(rs, 32);
      lrow += rs;

      short* pw = &p_lds[w][0];
#pragma unroll
      for (int mb = 0; mb < 4; mb++)
#pragma unroll
        for (int jh = 0; jh < 2; jh++) {
          const int m = mb * 16 + g * 4 + jh * 2;
          unsigned int pk = ((unsigned int)(unsigned short)f2bf(p[mb][jh * 2 + 1]) << 16)
                          |  (unsigned int)(unsigned short)f2bf(p[mb][jh * 2]);
          *(unsigned int*)&pw[c * 64 + (m ^ csw)] = pk;
        }

      __builtin_amdgcn_s_setprio(1);
#pragma unroll
      for (int kb = 0; kb < 2; kb++) {
        const int m0 = kb * 32 + g * 8;
        short8 pa = *(const short8*)&pw[c * 64 + (m0 ^ csw)];
#pragma unroll
        for (int db = 0; db < 4; db++) {
          const int d = db * 16 + c;
          short8 vf = *(const short8*)&vl[d * 64 + (m0 ^ ((d & 7) << 3))];
          oacc[db] = __builtin_amdgcn_mfma_f32_16x16x32_bf16(pa, vf, oacc[db], 0, 0, 0);
        }
      }
      __builtin_amdgcn_s_setprio(0);
    }
    __syncthreads();
  }

  float linv[4];
#pragma unroll
  for (int j = 0; j < 4; j++) linv[j] = 1.f / __shfl(lrow, g * 4 + j);
#pragma unroll
  for (int j = 0; j < 4; j++) {
    short* op = ctx + bhq + (size_t)(qbase + w * 16 + g * 4 + j) * EMBED;
#pragma unroll
    for (int db = 0; db < 4; db++)
      op[db * 16 + c] = f2bf(oacc[db][j] * linv[j]);
  }
}

extern "C" void kernel_launch(void* const* d_in, const int* in_sizes, int n_in,
                              void* d_out, int out_size, void* d_ws, size_t ws_size,
                              hipStream_t stream) {
  const float* x     = (const float*)d_in[0];
  const float* Wq    = (const float*)d_in[1];
  const float* bq    = (const float*)d_in[2];
  const float* Wk    = (const float*)d_in[3];
  const float* bk    = (const float*)d_in[4];
  const float* Wv    = (const float*)d_in[5];
  const float* bv    = (const float*)d_in[6];
  const float* Wo    = (const float*)d_in[7];
  const float* bo    = (const float*)d_in[8];
  const float* gamma = (const float*)d_in[9];
  const float* beta  = (const float*)d_in[10];
  const float* relb  = (const float*)d_in[11];
  float* out = (float*)d_out;

  char* ws = (char*)d_ws;
  short* xn  = (short*)ws; ws += (size_t)NTOK * EMBED * 2;   // reused as vtb after QKV GEMM
  short* wqb = (short*)ws; ws += (size_t)EMBED * EMBED * 2;  // wqb|wkb|wvb contiguous = Wcat
  short* wkb = (short*)ws; ws += (size_t)EMBED * EMBED * 2;
  short* wvb = (short*)ws; ws += (size_t)EMBED * EMBED * 2;
  short* wob = (short*)ws; ws += (size_t)EMBED * EMBED * 2;
  short* qb  = (short*)ws; ws += (size_t)NTOK * EMBED * 2;
  short* kb_ = (short*)ws; ws += (size_t)NTOK * EMBED * 2;
  short* vb  = (short*)ws; ws += (size_t)NTOK * EMBED * 2;
  short* ctx = (short*)ws; ws += (size_t)NTOK * EMBED * 2;
  short* vtb = xn;

  lncast_kernel<<<dim3(NTOK + 4096), dim3(256), 0, stream>>>(
      x, gamma, beta, xn, Wq, Wk, Wv, Wo, wqb, wkb, wvb, wob);
  qkv2ph_kernel<<<dim3(512), dim3(512), 0, stream>>>(
      xn, wqb, bq, bk, bv, qb, kb_, vb);
  vtrans_kernel<<<dim3(32, 32), dim3(256), 0, stream>>>(vb, vtb);
  attn_kernel<<<dim3(512), dim3(512), 0, stream>>>(qb, kb_, vtb, relb, ctx);
  gemm_kernel<true><<<dim3(8, 32), dim3(256), 0, stream>>>(ctx, wob, bo, (void*)out);
}

// Round 9
// 208.836 us; speedup vs baseline: 1.1565x; 1.0126x over previous
//
#include <hip/hip_runtime.h>
#include <hip/hip_bf16.h>

#define EMBED 1024
#define NHEADS 16
#define HDIM 64
#define NB 2
#define NSEQ 2048
#define NTOK (NB*NSEQ)   // 4096

using short8  = __attribute__((ext_vector_type(8))) short;
using short4v = __attribute__((ext_vector_type(4))) short;
using f32x4   = __attribute__((ext_vector_type(4))) float;

#define INV_LN2 1.4426950408889634f

__device__ __forceinline__ short f2bf(float x) {
  __hip_bfloat16 h = __float2bfloat16(x);
  short s;
  __builtin_memcpy(&s, &h, 2);
  return s;
}

#define GLDS16(gp, lp) __builtin_amdgcn_global_load_lds( \
    (const __attribute__((address_space(1))) unsigned int*)(const void*)(gp), \
    (__attribute__((address_space(3))) unsigned int*)(void*)(lp), 16, 0, 0)

// ---------------- fused LayerNorm + weight cast ----------------
__global__ __launch_bounds__(256) void lncast_kernel(const float* __restrict__ x,
    const float* __restrict__ gamma, const float* __restrict__ beta, short* __restrict__ xn,
    const float* __restrict__ Wq, const float* __restrict__ Wk,
    const float* __restrict__ Wv, const float* __restrict__ Wo,
    short* __restrict__ wqb, short* __restrict__ wkb,
    short* __restrict__ wvb, short* __restrict__ wob) {
  const int bid = blockIdx.x;
  const int tid = threadIdx.x;
  if (bid < NTOK) {
    const float* xr = x + (size_t)bid * EMBED;
    float4 v = *(const float4*)(xr + tid * 4);
    float s  = v.x + v.y + v.z + v.w;
    float s2 = v.x*v.x + v.y*v.y + v.z*v.z + v.w*v.w;
#pragma unroll
    for (int off = 32; off; off >>= 1) {
      s  += __shfl_down(s, off);
      s2 += __shfl_down(s2, off);
    }
    __shared__ float red[8];
    const int wv = tid >> 6, ln = tid & 63;
    if (ln == 0) { red[wv] = s; red[4 + wv] = s2; }
    __syncthreads();
    s  = red[0] + red[1] + red[2] + red[3];
    s2 = red[4] + red[5] + red[6] + red[7];
    const float mu  = s * (1.0f / EMBED);
    const float var = s2 * (1.0f / EMBED) - mu * mu;
    const float inv = rsqrtf(var + 1e-5f);
    float4 g  = *(const float4*)(gamma + tid * 4);
    float4 bt = *(const float4*)(beta + tid * 4);
    short4v o;
    o[0] = f2bf((v.x - mu) * inv * g.x + bt.x);
    o[1] = f2bf((v.y - mu) * inv * g.y + bt.y);
    o[2] = f2bf((v.z - mu) * inv * g.z + bt.z);
    o[3] = f2bf((v.w - mu) * inv * g.w + bt.w);
    *(short4v*)(xn + (size_t)bid * EMBED + tid * 4) = o;
  } else {
    const int i = (bid - NTOK) * 1024 + tid * 4;
    const int wsel = i >> 20;
    const int off  = i & 1048575;
    const float* s = (wsel == 0) ? Wq : (wsel == 1) ? Wk : (wsel == 2) ? Wv : Wo;
    short* o       = (wsel == 0) ? wqb : (wsel == 1) ? wkb : (wsel == 2) ? wvb : wob;
    float4 v = *(const float4*)(s + off);
    short4v r;
    r[0] = f2bf(v.x); r[1] = f2bf(v.y); r[2] = f2bf(v.z); r[3] = f2bf(v.w);
    *(short4v*)(o + off) = r;
  }
}

// ---------------- QKV GEMM: 128x192 tile, BK=64, 8 waves, 2-phase dbuf ----------------
__global__ __launch_bounds__(512, 4) void qkv2ph_kernel(
    const short* __restrict__ A, const short* __restrict__ Wcat,
    const float* __restrict__ b0, const float* __restrict__ b1, const float* __restrict__ b2,
    short* __restrict__ O0, short* __restrict__ O1, short* __restrict__ O2) {
  constexpr int K = 1024;
  const int orig = blockIdx.x;                  // 512 = 8 * 64, bijective XCD swizzle
  const int swzb = (orig & 7) * 64 + (orig >> 3);
  const int tn = swzb & 15, tm = swzb >> 4;

  const int tid = threadIdx.x;
  const int w = tid >> 6, lane = tid & 63;
  const int wr = w >> 2, wc = w & 3;            // 2(M) x 4(N); per-wave 64x48
  const int g = lane >> 4, c = lane & 15;

  __shared__ short As[2][128 * 64];
  __shared__ short Bs[2][192 * 64];

  f32x4 acc[4][3];
#pragma unroll
  for (int i = 0; i < 4; i++)
#pragma unroll
    for (int j = 0; j < 3; j++) acc[i][j] = (f32x4){0.f, 0.f, 0.f, 0.f};

  const int sr  = tid >> 3;                     // 0..63
  const int sc8 = (tid & 7) * 8;
  const int ssw = (sr & 7) << 3;
  const short* ga = A    + (size_t)(tm * 128) * K;
  const short* gb = Wcat + (size_t)(tn * 192) * K;

  auto STAGE = [&](int buf, int kt) {
#pragma unroll
    for (int u = 0; u < 2; u++) {
      const int row = u * 64 + sr;
      GLDS16(ga + (size_t)row * K + kt * 64 + (sc8 ^ ssw), &As[buf][row * 64 + sc8]);
    }
#pragma unroll
    for (int u = 0; u < 3; u++) {
      const int row = u * 64 + sr;
      GLDS16(gb + (size_t)row * K + kt * 64 + (sc8 ^ ssw), &Bs[buf][row * 64 + sc8]);
    }
  };

  STAGE(0, 0);
  __syncthreads();

  for (int kt = 0; kt < 16; ++kt) {
    const int cur = kt & 1;
    if (kt + 1 < 16) STAGE(cur ^ 1, kt + 1);
    const short* as = As[cur];
    const short* bs = Bs[cur];
#pragma unroll
    for (int ks = 0; ks < 2; ks++) {
      short8 af[4], bf[3];
#pragma unroll
      for (int mi = 0; mi < 4; mi++) {
        const int row = wr * 64 + mi * 16 + c;
        af[mi] = *(const short8*)&as[row * 64 + ((ks * 32 + g * 8) ^ ((row & 7) << 3))];
      }
#pragma unroll
      for (int ni = 0; ni < 3; ni++) {
        const int row = wc * 48 + ni * 16 + c;
        bf[ni] = *(const short8*)&bs[row * 64 + ((ks * 32 + g * 8) ^ ((row & 7) << 3))];
      }
      __builtin_amdgcn_s_setprio(1);
#pragma unroll
      for (int mi = 0; mi < 4; mi++)
#pragma unroll
        for (int ni = 0; ni < 3; ni++)
          acc[mi][ni] = __builtin_amdgcn_mfma_f32_16x16x32_bf16(af[mi], bf[ni], acc[mi][ni], 0, 0, 0);
      __builtin_amdgcn_s_setprio(0);
    }
    __syncthreads();
  }

#pragma unroll
  for (int ni = 0; ni < 3; ni++) {
    const int col = tn * 192 + wc * 48 + ni * 16 + c;
    const int sel = col >> 10, lc = col & 1023;
    short* O        = (sel == 0) ? O0 : (sel == 1) ? O1 : O2;
    const float* bb = (sel == 0) ? b0 : (sel == 1) ? b1 : b2;
    const float bsv = bb[lc];
#pragma unroll
    for (int mi = 0; mi < 4; mi++) {
      const int row = tm * 128 + wr * 64 + mi * 16 + g * 4;
#pragma unroll
      for (int j = 0; j < 4; j++)
        O[(size_t)(row + j) * 1024 + lc] = f2bf(acc[mi][ni][j] + bsv);
    }
  }
}

// ---------------- proj GEMM: 128x64 tile, BK=64, 4 waves, 2-phase dbuf, f32 out ----------------
__global__ __launch_bounds__(256, 2) void proj2ph_kernel(
    const short* __restrict__ A, const short* __restrict__ Bw,
    const float* __restrict__ bias, float* __restrict__ Cout) {
  constexpr int K = 1024;
  const int orig = blockIdx.x;                  // 512 = 8 * 64, bijective XCD swizzle
  const int swzb = (orig & 7) * 64 + (orig >> 3);
  const int tn = swzb & 15, tm = swzb >> 4;     // 16 x 32

  const int tid = threadIdx.x;
  const int w = tid >> 6, lane = tid & 63;
  const int wr = w >> 1, wc = w & 1;            // 2(M) x 2(N); per-wave 64x32
  const int g = lane >> 4, c = lane & 15;

  __shared__ short As[2][128 * 64];
  __shared__ short Bs[2][64 * 64];

  f32x4 acc[4][2];
#pragma unroll
  for (int i = 0; i < 4; i++)
#pragma unroll
    for (int j = 0; j < 2; j++) acc[i][j] = (f32x4){0.f, 0.f, 0.f, 0.f};

  const int sr8 = tid >> 3;                     // 0..31
  const int sd0 = (tid & 7) * 8;
  const short* ga = A  + (size_t)(tm * 128) * K;
  const short* gb = Bw + (size_t)(tn * 64) * K;

  auto STAGE = [&](int buf, int kt) {
#pragma unroll
    for (int i = 0; i < 4; i++) {
      const int row = i * 32 + sr8;
      const int sw = (row & 7) << 3;
      GLDS16(ga + (size_t)row * K + kt * 64 + (sd0 ^ sw), &As[buf][row * 64 + sd0]);
    }
#pragma unroll
    for (int i = 0; i < 2; i++) {
      const int row = i * 32 + sr8;
      const int sw = (row & 7) << 3;
      GLDS16(gb + (size_t)row * K + kt * 64 + (sd0 ^ sw), &Bs[buf][row * 64 + sd0]);
    }
  };

  STAGE(0, 0);
  __syncthreads();

  for (int kt = 0; kt < 16; ++kt) {
    const int cur = kt & 1;
    if (kt + 1 < 16) STAGE(cur ^ 1, kt + 1);
    const short* as = As[cur];
    const short* bs = Bs[cur];
#pragma unroll
    for (int ks = 0; ks < 2; ks++) {
      short8 af[4], bf[2];
#pragma unroll
      for (int mi = 0; mi < 4; mi++) {
        const int row = wr * 64 + mi * 16 + c;
        af[mi] = *(const short8*)&as[row * 64 + ((ks * 32 + g * 8) ^ ((row & 7) << 3))];
      }
#pragma unroll
      for (int ni = 0; ni < 2; ni++) {
        const int row = wc * 32 + ni * 16 + c;
        bf[ni] = *(const short8*)&bs[row * 64 + ((ks * 32 + g * 8) ^ ((row & 7) << 3))];
      }
      __builtin_amdgcn_s_setprio(1);
#pragma unroll
      for (int mi = 0; mi < 4; mi++)
#pragma unroll
        for (int ni = 0; ni < 2; ni++)
          acc[mi][ni] = __builtin_amdgcn_mfma_f32_16x16x32_bf16(af[mi], bf[ni], acc[mi][ni], 0, 0, 0);
      __builtin_amdgcn_s_setprio(0);
    }
    __syncthreads();
  }

#pragma unroll
  for (int ni = 0; ni < 2; ni++) {
    const int col = tn * 64 + wc * 32 + ni * 16 + c;
    const float bsv = bias[col];
#pragma unroll
    for (int mi = 0; mi < 4; mi++) {
      const int row = tm * 128 + wr * 64 + mi * 16 + g * 4;
#pragma unroll
      for (int j = 0; j < 4; j++)
        Cout[(size_t)(row + j) * 1024 + col] = acc[mi][ni][j] + bsv;
    }
  }
}

// ---------------- V transpose: [n][h*64+d] -> [b][h][d][n(2048)] ----------------
__global__ __launch_bounds__(256) void vtrans_kernel(const short* __restrict__ vb,
                                                     short* __restrict__ vt) {
  const int n0 = blockIdx.x * 64;
  const int bh = blockIdx.y;
  const int b = bh >> 4, h = bh & 15;
  const int tid = threadIdx.x;
  __shared__ short tl[64 * 68];

  const int r  = tid >> 3;
  const int c8 = (tid & 7) * 8;
#pragma unroll
  for (int i = 0; i < 2; i++) {
    const int row = r + i * 32;
    short8 v = *(const short8*)(vb + (size_t)(b * NSEQ + n0 + row) * EMBED + h * 64 + c8);
    *(short8*)&tl[row * 68 + c8] = v;
  }
  __syncthreads();
  const int d  = tid >> 2;
  const int ns = (tid & 3) * 16;
  short8 o0, o1;
#pragma unroll
  for (int e = 0; e < 8; e++) {
    o0[e] = tl[(ns + e) * 68 + d];
    o1[e] = tl[(ns + 8 + e) * 68 + d];
  }
  short* dst = vt + ((size_t)((b * 16 + h) * 64 + d)) * 2048 + n0 + ns;
  *(short8*)dst = o0;
  *(short8*)(dst + 8) = o1;
}

// ---------------- Flash attention: 4 waves x 32 q-rows (2 groups of 16) ----------------
// K/U/V fragment reads shared across the wave's 2 q-groups (1.8x less LDS read traffic).
__global__ __launch_bounds__(256, 2) void attn_kernel(
    const short* __restrict__ Qm, const short* __restrict__ Km, const short* __restrict__ Vt,
    const float* __restrict__ relb, short* __restrict__ ctx) {
  const int bid = blockIdx.x;
  const int bh  = bid & 31;
  const int idx = bid >> 5;
  const int qpair = (idx < 8) ? (15 - idx) : (idx - 8);
  const int b = bh >> 4, h = bh & 15;
  const int tid = threadIdx.x, w = tid >> 6, lane = tid & 63;
  const int g = lane >> 4, c = lane & 15;
  constexpr float S31 = 31.0f / 2047.0f;
  constexpr float CSC = 0.125f * INV_LN2;

  __shared__ short k_lds[2][64 * 64];   // [m][d ^ ((m&7)<<3)]
  __shared__ short vt_lds[2][64 * 64];  // [d][m ^ ((d&7)<<3)]
  __shared__ short p_lds[4][32 * 64];   // per-wave P: [q(32)][m ^ ((q&7)<<3)]
  __shared__ short rbf[128 * 32];       // q-interp'd bias * 8, bf16
  __shared__ short u_lds[2][64 * 40];   // per-tile m-interp weights

  const int qbase = qpair * 128;
  const size_t bhq = (size_t)b * NSEQ * EMBED + h * HDIM;
  const short* vtb = Vt + (size_t)((b << 4) + h) * 64 * 2048;

  // Q fragments for the wave's two 16-row groups
  short8 qf[2][2];
#pragma unroll
  for (int grp = 0; grp < 2; grp++) {
    const short* qp = Qm + bhq + (size_t)(qbase + w * 32 + grp * 16 + c) * EMBED;
    qf[grp][0] = *(const short8*)(qp + g * 8);
    qf[grp][1] = *(const short8*)(qp + 32 + g * 8);
  }

  const int sr8 = tid >> 3;             // 0..31
  const int sd0 = (tid & 7) * 8;

  auto buildU = [&](int buf, int kv) {
    if (tid < 64) {
      short* ur = &u_lds[buf][tid * 40];
      *(int4*)&ur[0]  = (int4){0, 0, 0, 0};
      *(int4*)&ur[8]  = (int4){0, 0, 0, 0};
      *(int4*)&ur[16] = (int4){0, 0, 0, 0};
      *(int4*)&ur[24] = (int4){0, 0, 0, 0};
      const int m = kv + tid;
      if (m != NSEQ - 1) {
        const float pos = m * S31;
        const int i0 = (int)pos;
        const float fr = pos - (float)i0;
        ur[i0]     = f2bf(1.0f - fr);
        ur[i0 + 1] = f2bf(fr);
      }
    }
  };

  // prologue: stage tile 0 (2 passes K + 2 passes V), build R, U
#pragma unroll
  for (int i = 0; i < 2; i++) {
    const int row = i * 32 + sr8;
    const int sw = (row & 7) << 3;
    GLDS16(Km + bhq + (size_t)row * EMBED + (sd0 ^ sw), &k_lds[0][row * 64 + sd0]);
    GLDS16(vtb + (size_t)row * 2048 + (sd0 ^ sw),       &vt_lds[0][row * 64 + sd0]);
  }
  for (int i = tid; i < 128 * 32; i += 256) {
    const int qr = i >> 5, jj = i & 31;
    const int qg0 = qbase + qr;
    float rv = 0.f;
    if (qg0 != NSEQ - 1) {
      const float pos = qg0 * S31;
      const int i0 = (int)pos;
      const int i1 = min(i0 + 1, 31);
      const float fr = pos - (float)i0;
      const float* T = relb + h * 1024;
      rv = ((1.f - fr) * T[i0 * 32 + jj] + fr * T[i1 * 32 + jj]) * 8.0f;
    }
    rbf[i] = f2bf(rv);
  }
  buildU(0, 0);
  __syncthreads();

  short8 rq[2];
#pragma unroll
  for (int grp = 0; grp < 2; grp++)
    rq[grp] = *(const short8*)&rbf[(w * 32 + grp * 16 + c) * 32 + g * 8];

  float mrow[2] = {-3.0e38f, -3.0e38f}, lrow[2] = {0.f, 0.f};
  f32x4 oacc[2][4];
#pragma unroll
  for (int grp = 0; grp < 2; grp++)
#pragma unroll
    for (int db = 0; db < 4; db++) oacc[grp][db] = (f32x4){0.f, 0.f, 0.f, 0.f};

  const int qgg[2] = {qbase + w * 32 + c, qbase + w * 32 + 16 + c};
  const int qhi = qbase + w * 32 + 31;
  const int csw = (c & 7) << 3;
  const int nkv = 2 * qpair + 2;

  for (int kt = 0; kt < nkv; kt++) {
    const int cur = kt & 1;
    const int kv0 = kt * 64;

    if (kt + 1 < nkv) {
#pragma unroll
      for (int i = 0; i < 2; i++) {
        const int row = i * 32 + sr8;
        const int sw = (row & 7) << 3;
        GLDS16(Km + bhq + (size_t)(kv0 + 64 + row) * EMBED + (sd0 ^ sw),
               &k_lds[cur ^ 1][row * 64 + sd0]);
        GLDS16(vtb + (size_t)row * 2048 + (kv0 + 64) + (sd0 ^ sw),
               &vt_lds[cur ^ 1][row * 64 + sd0]);
      }
      buildU(cur ^ 1, kv0 + 64);
    }

    if (kv0 <= qhi) {
      const short* kl = &k_lds[cur][0];
      const short* vl = &vt_lds[cur][0];
      const short* ul = &u_lds[cur][0];

      f32x4 st[2][4];
#pragma unroll
      for (int grp = 0; grp < 2; grp++)
#pragma unroll
        for (int mb = 0; mb < 4; mb++) st[grp][mb] = (f32x4){0.f, 0.f, 0.f, 0.f};

      __builtin_amdgcn_s_setprio(1);
#pragma unroll
      for (int kh = 0; kh < 2; kh++) {
        const int dk = kh * 32 + g * 8;
#pragma unroll
        for (int mb = 0; mb < 4; mb++) {
          const int row = mb * 16 + c;
          short8 kf = *(const short8*)&kl[row * 64 + (dk ^ ((row & 7) << 3))];
          st[0][mb] = __builtin_amdgcn_mfma_f32_16x16x32_bf16(kf, qf[0][kh], st[0][mb], 0, 0, 0);
          st[1][mb] = __builtin_amdgcn_mfma_f32_16x16x32_bf16(kf, qf[1][kh], st[1][mb], 0, 0, 0);
        }
      }
#pragma unroll
      for (int mb = 0; mb < 4; mb++) {
        short8 uf = *(const short8*)&ul[(mb * 16 + c) * 40 + g * 8];
        st[0][mb] = __builtin_amdgcn_mfma_f32_16x16x32_bf16(uf, rq[0], st[0][mb], 0, 0, 0);
        st[1][mb] = __builtin_amdgcn_mfma_f32_16x16x32_bf16(uf, rq[1], st[1][mb], 0, 0, 0);
      }
      __builtin_amdgcn_s_setprio(0);

      float pmax[2];
#pragma unroll
      for (int grp = 0; grp < 2; grp++) {
        const int qg = qgg[grp];
        if (kv0 + 63 > qg) {
#pragma unroll
          for (int mb = 0; mb < 4; mb++)
#pragma unroll
            for (int j = 0; j < 4; j++) {
              const int mg = kv0 + mb * 16 + g * 4 + j;
              if (mg > qg) st[grp][mb][j] = -1.0e38f;
            }
        }
        float pmr = -3.0e38f;
#pragma unroll
        for (int mb = 0; mb < 4; mb++)
#pragma unroll
          for (int j = 0; j < 4; j++) pmr = fmaxf(pmr, st[grp][mb][j]);
        float pm = pmr * CSC;
        pm = fmaxf(pm, __shfl_xor(pm, 16));
        pm = fmaxf(pm, __shfl_xor(pm, 32));
        pmax[grp] = pm;
      }

      if (!__all((pmax[0] - mrow[0] <= 11.6f) && (pmax[1] - mrow[1] <= 11.6f))) {
#pragma unroll
        for (int grp = 0; grp < 2; grp++) {
          const float mnew = fmaxf(mrow[grp], pmax[grp]);
          const float al = exp2f(mrow[grp] - mnew);
          mrow[grp] = mnew;
          lrow[grp] *= al;
          float alj[4];
#pragma unroll
          for (int j = 0; j < 4; j++) alj[j] = __shfl(al, g * 4 + j);
#pragma unroll
          for (int db = 0; db < 4; db++)
#pragma unroll
            for (int j = 0; j < 4; j++) oacc[grp][db][j] *= alj[j];
        }
      }

      float p[2][4][4];
#pragma unroll
      for (int grp = 0; grp < 2; grp++) {
        float rs = 0.f;
#pragma unroll
        for (int mb = 0; mb < 4; mb++)
#pragma unroll
          for (int j = 0; j < 4; j++) {
            const float pe = exp2f(fmaf(st[grp][mb][j], CSC, -mrow[grp]));
            p[grp][mb][j] = pe;
            rs += pe;
          }
        rs += __shfl_xor(rs, 16);
        rs += __shfl_xor(rs, 32);
        lrow[grp] += rs;
      }

      short* pw = &p_lds[w][0];
#pragma unroll
      for (int grp = 0; grp < 2; grp++)
#pragma unroll
        for (int mb = 0; mb < 4; mb++)
#pragma unroll
          for (int jh = 0; jh < 2; jh++) {
            const int m = mb * 16 + g * 4 + jh * 2;
            unsigned int pk = ((unsigned int)(unsigned short)f2bf(p[grp][mb][jh * 2 + 1]) << 16)
                            |  (unsigned int)(unsigned short)f2bf(p[grp][mb][jh * 2]);
            *(unsigned int*)&pw[(grp * 16 + c) * 64 + (m ^ csw)] = pk;
          }

      __builtin_amdgcn_s_setprio(1);
#pragma unroll
      for (int kb = 0; kb < 2; kb++) {
        const int m0 = kb * 32 + g * 8;
        short8 pa0 = *(const short8*)&pw[c * 64 + (m0 ^ csw)];
        short8 pa1 = *(const short8*)&pw[(16 + c) * 64 + (m0 ^ csw)];
#pragma unroll
        for (int db = 0; db < 4; db++) {
          const int d = db * 16 + c;
          short8 vf = *(const short8*)&vl[d * 64 + (m0 ^ ((d & 7) << 3))];
          oacc[0][db] = __builtin_amdgcn_mfma_f32_16x16x32_bf16(pa0, vf, oacc[0][db], 0, 0, 0);
          oacc[1][db] = __builtin_amdgcn_mfma_f32_16x16x32_bf16(pa1, vf, oacc[1][db], 0, 0, 0);
        }
      }
      __builtin_amdgcn_s_setprio(0);
    }
    __syncthreads();
  }

#pragma unroll
  for (int grp = 0; grp < 2; grp++)
#pragma unroll
    for (int j = 0; j < 4; j++) {
      const float linv = 1.f / __shfl(lrow[grp], g * 4 + j);
      short* op = ctx + bhq + (size_t)(qbase + w * 32 + grp * 16 + g * 4 + j) * EMBED;
#pragma unroll
      for (int db = 0; db < 4; db++)
        op[db * 16 + c] = f2bf(oacc[grp][db][j] * linv);
    }
}

extern "C" void kernel_launch(void* const* d_in, const int* in_sizes, int n_in,
                              void* d_out, int out_size, void* d_ws, size_t ws_size,
                              hipStream_t stream) {
  const float* x     = (const float*)d_in[0];
  const float* Wq    = (const float*)d_in[1];
  const float* bq    = (const float*)d_in[2];
  const float* Wk    = (const float*)d_in[3];
  const float* bk    = (const float*)d_in[4];
  const float* Wv    = (const float*)d_in[5];
  const float* bv    = (const float*)d_in[6];
  const float* Wo    = (const float*)d_in[7];
  const float* bo    = (const float*)d_in[8];
  const float* gamma = (const float*)d_in[9];
  const float* beta  = (const float*)d_in[10];
  const float* relb  = (const float*)d_in[11];
  float* out = (float*)d_out;

  char* ws = (char*)d_ws;
  short* xn  = (short*)ws; ws += (size_t)NTOK * EMBED * 2;   // reused as vtb after QKV GEMM
  short* wqb = (short*)ws; ws += (size_t)EMBED * EMBED * 2;  // wqb|wkb|wvb contiguous = Wcat
  short* wkb = (short*)ws; ws += (size_t)EMBED * EMBED * 2;
  short* wvb = (short*)ws; ws += (size_t)EMBED * EMBED * 2;
  short* wob = (short*)ws; ws += (size_t)EMBED * EMBED * 2;
  short* qb  = (short*)ws; ws += (size_t)NTOK * EMBED * 2;
  short* kb_ = (short*)ws; ws += (size_t)NTOK * EMBED * 2;
  short* vb  = (short*)ws; ws += (size_t)NTOK * EMBED * 2;
  short* ctx = (short*)ws; ws += (size_t)NTOK * EMBED * 2;
  short* vtb = xn;

  lncast_kernel<<<dim3(NTOK + 4096), dim3(256), 0, stream>>>(
      x, gamma, beta, xn, Wq, Wk, Wv, Wo, wqb, wkb, wvb, wob);
  qkv2ph_kernel<<<dim3(512), dim3(512), 0, stream>>>(
      xn, wqb, bq, bk, bv, qb, kb_, vb);
  vtrans_kernel<<<dim3(32, 32), dim3(256), 0, stream>>>(vb, vtb);
  attn_kernel<<<dim3(512), dim3(256), 0, stream>>>(qb, kb_, vtb, relb, ctx);
  proj2ph_kernel<<<dim3(512), dim3(256), 0, stream>>>(ctx, wob, bo, out);
}